// Round 9
// baseline (234.760 us; speedup 1.0000x reference)
//
#include <hip/hip_runtime.h>

typedef __attribute__((ext_vector_type(8))) short    v8s;   // 8 bf16 (4 VGPR)
typedef __attribute__((ext_vector_type(4))) float    f4;
typedef __attribute__((ext_vector_type(2))) float    f2;
typedef __attribute__((ext_vector_type(2))) unsigned u32x2;

#define MFMA16 __builtin_amdgcn_mfma_f32_16x16x32_bf16

// ---- d_ws layout ----
// bf16 section (ushort units). ALL weight tiles are FRAGMENT-ORDERED:
//   ws[base + ((wt*KT + kt)*64 + lane)*8 + j]  holds W[n=wt*16+c][k=kt*32+q*8+j]
// -> every wf load is lane-consecutive 16B (coalesced).
#define AW1T 0        // KT=4: 16 frags
#define TW1T 8192
#define CW1T 16384
#define AW2T 24576    // KT=2: 8 frags
#define TW2T 28672
#define CW2T 32768
#define MWT  36864    // KT=2, NWT=1 (rows 8..15 zero)
#define HWT  37888    // KT=2, NWT=3 (diag-first-permuted, 36..47 zero)
#define FW1XT 40960   // + i*4096 : KT=4, NWT=2
#define FW2T  57344   // + i*512  : single frag [lane][8]
#define WS_BF16_TOTAL 59392
// f32 section (float units, base = d_ws + WS_BF16_TOTAL*2)
#define W1CTO 0       // + i*128 : [32][4]  (cond weights, row=neuron, k=0..3)
#define HBPO  512     // [48] hb permuted

#define LOG2PI 1.83787706640934548356f
#define EPSF   1.1920928955078125e-07f

__device__ __constant__ int PERM[36] = {0,2,5,9,14,20,27,35,
  1,3,4,6,7,8,10,11,12,13,15,16,17,18,19,21,22,23,24,25,26,28,29,30,31,32,33,34};

__device__ __forceinline__ float ubits(unsigned u){union{unsigned u;float f;}c;c.u=u;return c.f;}
__device__ __forceinline__ unsigned fbits(float f){union{float f;unsigned u;}c;c.f=f;return c.u;}
__device__ __forceinline__ float rcpf(float x){ return __builtin_amdgcn_rcpf(x); }
__device__ __forceinline__ float siluf(float v){ return v * rcpf(1.f + __expf(-v)); }
__device__ __forceinline__ unsigned pk2(float a,float b){            // 2x f32 -> packed bf16 (RTNE)
  unsigned ua=fbits(a); ua+=0x7fffu+((ua>>16)&1u);
  unsigned ub=fbits(b); ub+=0x7fffu+((ub>>16)&1u);
  return (ua>>16)|(ub&0xffff0000u);
}
__device__ __forceinline__ unsigned short f2bu(float a){
  unsigned ua=fbits(a); ua+=0x7fffu+((ua>>16)&1u);
  return (unsigned short)(ua>>16);
}
__device__ __forceinline__ float b2f16(unsigned short h){ return ubits(((unsigned)h)<<16); }
__device__ __forceinline__ float qsum(float v){                       // sum over the 4 quads
  v += __shfl_xor(v,16,64); v += __shfl_xor(v,32,64); return v;
}
// XOR-swizzled halfword offset into a [32][64]-bf16 tile
__device__ __forceinline__ int swz(int row, int blk){ return row*64 + ((blk ^ (row&7))*8); }
// same for the [32][128]-bf16 x tile
__device__ __forceinline__ int swzx(int row, int blk){ return row*128 + ((blk ^ (row&7))*8); }

// ============ prep: fragment-order/pad/permute weights into ws (bf16) =======
__global__ __launch_bounds__(256)
void prep_kernel(const float* __restrict__ aW1, const float* __restrict__ aW2,
                 const float* __restrict__ mW,  const float* __restrict__ tW1,
                 const float* __restrict__ tW2, const float* __restrict__ hW,
                 const float* __restrict__ hb,  const float* __restrict__ cW1,
                 const float* __restrict__ cW2, const float* __restrict__ fW1,
                 const float* __restrict__ fW2,
                 unsigned short* __restrict__ ws16, float* __restrict__ wsf)
{
  const int tid = blockIdx.x*256 + threadIdx.x;
  const int stride = gridDim.x*256;
  for (int idx=tid; idx<64*128; idx+=stride){
    int f=idx>>9, r=idx&511, lane=r>>3, j=idx&7;
    int wt=f>>2, kt=f&3, c=lane&15, q=lane>>4;
    int n=wt*16+c, k=kt*32+q*8+j;
    ws16[AW1T+idx]=f2bu(aW1[k*64+n]);
    ws16[TW1T+idx]=f2bu(tW1[k*64+n]);
    ws16[CW1T+idx]=f2bu(cW1[k*64+n]);
  }
  for (int idx=tid; idx<64*64; idx+=stride){
    int f=idx>>9, r=idx&511, lane=r>>3, j=idx&7;
    int wt=f>>1, kt=f&1, c=lane&15, q=lane>>4;
    int n=wt*16+c, k=kt*32+q*8+j;
    ws16[AW2T+idx]=f2bu(aW2[k*64+n]);
    ws16[TW2T+idx]=f2bu(tW2[k*64+n]);
    ws16[CW2T+idx]=f2bu(cW2[k*64+n]);
  }
  for (int idx=tid; idx<16*64; idx+=stride){
    int f=idx>>9, r=idx&511, lane=r>>3, j=idx&7;
    int kt=f, c=lane&15, q=lane>>4;
    int n=c, k=kt*32+q*8+j;
    ws16[MWT+idx]=f2bu(n<8 ? mW[k*8+n] : 0.f);
  }
  for (int idx=tid; idx<48*64; idx+=stride){
    int f=idx>>9, r=idx&511, lane=r>>3, j=idx&7;
    int wt=f>>1, kt=f&1, c=lane&15, q=lane>>4;
    int n=wt*16+c, k=kt*32+q*8+j;
    ws16[HWT+idx]=f2bu(n<36 ? hW[k*36+PERM[n]] : 0.f);
  }
  for (int idx=tid; idx<4*32*128; idx+=stride){
    int i=idx>>12, rem=idx&4095;
    int f=rem>>9, r=rem&511, lane=r>>3, j=idx&7;
    int wt=f>>2, kt=f&3, c=lane&15, q=lane>>4;
    int n=wt*16+c, k=kt*32+q*8+j;
    ws16[FW1XT+idx]=f2bu(fW1[i*4224 + (4+k)*32 + n]);
  }
  for (int idx=tid; idx<4*16*32; idx+=stride){
    int i=idx>>9, r=idx&511, lane=r>>3, j=idx&7;
    int c=lane&15, q=lane>>4;
    int k=q*8+j;
    ws16[FW2T+idx]=f2bu(c<8 ? fW2[i*256 + k*8 + c] : 0.f);
  }
  for (int idx=tid; idx<4*32*4; idx+=stride){
    int i=idx>>7, rem=idx&127, n=rem>>2, k=rem&3;
    wsf[W1CTO+idx]=fW1[i*4224 + k*32 + n];
  }
  for (int idx=tid; idx<48; idx+=stride)
    wsf[HBPO+idx] = idx<36 ? hb[PERM[idx]] : 0.f;
}

// ============ GEMM helpers (outputs transposed: rows=neurons, cols=elems) ===
template<int NWT>
__device__ __forceinline__ void gemmX(const unsigned short* __restrict__ Wt,
                                      const v8s* __restrict__ xf,
                                      f4 (*acc)[2], int lane)
{
#pragma unroll
  for (int kt=0; kt<4; ++kt){
    v8s wf[NWT];
#pragma unroll
    for (int wt=0; wt<NWT; ++wt)
      wf[wt] = *(const v8s*)(Wt + ((wt*4 + kt)*64 + lane)*8);
#pragma unroll
    for (int wt=0; wt<NWT; ++wt)
#pragma unroll
      for (int et=0; et<2; ++et)
        acc[wt][et] = MFMA16(wf[wt], xf[et*4+kt], acc[wt][et], 0,0,0);
  }
}

template<int NWT>
__device__ __forceinline__ void gemmH(const unsigned short* __restrict__ Wt,
                                      const unsigned short* __restrict__ actL,
                                      f4 (*acc)[2], int lane, int c, int q)
{
#pragma unroll
  for (int kt=0; kt<2; ++kt){
    v8s wf[NWT];
#pragma unroll
    for (int wt=0; wt<NWT; ++wt)
      wf[wt] = *(const v8s*)(Wt + ((wt*2 + kt)*64 + lane)*8);
    v8s af[2];
#pragma unroll
    for (int et=0; et<2; ++et)
      af[et] = *(const v8s*)(actL + swz(et*16+c, kt*4+q));
#pragma unroll
    for (int wt=0; wt<NWT; ++wt)
#pragma unroll
      for (int et=0; et<2; ++et)
        acc[wt][et] = MFMA16(wf[wt], af[et], acc[wt][et], 0,0,0);
  }
}

// ============ main: 32 elems/block, 2 waves: chain split =====================
// R8 confirmed chain-bound (split: 117->73us). R9: break the remaining FALSE
// dependency in w1 phase B — t-chain and critic-chain are data-independent but
// shared act1; separate act2 buffer + interleaved issue -> ILP. Also hoist
// action/z_rpo loads to prologue (were ~500cyc of L2 latency on w0's path).
__global__ __launch_bounds__(128) __attribute__((amdgpu_waves_per_eu(3, 4)))
void policy_kernel(
    const float* __restrict__ x,    const float* __restrict__ action, const float* __restrict__ z_rpo,
    const float* __restrict__ cb1,  const float* __restrict__ c_rms,  const float* __restrict__ cb2,
    const float* __restrict__ cW3,  const float* __restrict__ cb3,
    const float* __restrict__ ab1,  const float* __restrict__ ab2,    const float* __restrict__ mb,
    const float* __restrict__ tb1,  const float* __restrict__ t_rms1, const float* __restrict__ tb2,
    const float* __restrict__ t_rms2,
    const float* __restrict__ fb1,  const float* __restrict__ fb2,
    const unsigned short* __restrict__ ws16, const float* __restrict__ wsf,
    float* __restrict__ out, const int Btot)
{
  const int tid  = threadIdx.x;
  const int wv   = tid >> 6;         // wave 0 / 1
  const int lane = tid & 63;
  const int q = lane >> 4, c = lane & 15;
  const int b0 = blockIdx.x << 5;

  __shared__ alignas(16) unsigned char smem[33152];
  float*          a2L  = (float*)smem;                     // [4][32][33] f32 flow pre-acts
  unsigned short* xL   = (unsigned short*)smem;            // [32][128] bf16 swizzled (prologue; aliases a2L)
  unsigned short* act0 = (unsigned short*)(smem + 16896);  // [32][64] bf16 swz (w0: actor / flow hid)
  unsigned short* act1 = (unsigned short*)(smem + 20992);  // [32][64] bf16 swz (w1: t-branch)
  unsigned short* act2 = (unsigned short*)(smem + 25088);  // [32][64] bf16 swz (w1: critic — breaks t|c false dep)
  unsigned short* triL = (unsigned short*)(smem + 29184);  // [32][36] bf16
  float*          nstL = (float*)(smem + 31488);           // [32][8] f32
  unsigned short* amL  = (unsigned short*)(smem + 32512);  // [32][8] bf16 (w0; stL aliases)
  float*          fldL = (float*)(smem + 33024);           // [32] f32

  // ---- stage x coalesced -> LDS (wave wv covers rows wv*16 .. wv*16+15) ----
  {
    const float* xb = x + (size_t)b0*128;
    const int rr = lane>>3, bb = (lane&7)*2;
#pragma unroll
    for (int rg=0; rg<2; ++rg){
      const int row = wv*16 + rg*8 + rr;
      const float* p = xb + row*128 + (lane&7)*16;
      f4 u0=*(const f4*)p, u1=*(const f4*)(p+4), u2=*(const f4*)(p+8), u3=*(const f4*)(p+12);
      union { unsigned u[4]; v8s v; } r0, r1;
      r0.u[0]=pk2(u0[0],u0[1]); r0.u[1]=pk2(u0[2],u0[3]);
      r0.u[2]=pk2(u1[0],u1[1]); r0.u[3]=pk2(u1[2],u1[3]);
      r1.u[0]=pk2(u2[0],u2[1]); r1.u[1]=pk2(u2[2],u2[3]);
      r1.u[2]=pk2(u3[0],u3[1]); r1.u[3]=pk2(u3[2],u3[3]);
      *(v8s*)(xL + swzx(row, bb  )) = r0.v;
      *(v8s*)(xL + swzx(row, bb+1)) = r1.v;
    }
  }
  // hoisted per-element loads (w0 lanes 0..31): overlap L2/HBM latency with actor
  const int l = lane;
  f4 a0v, a1v, zr0v, zr1v;
  if (wv==0 && l<32){
    const size_t bb = (size_t)(b0+l)*8;
    a0v=*(const f4*)(action+bb); a1v=*(const f4*)(action+bb+4);
    zr0v=*(const f4*)(z_rpo+bb); zr1v=*(const f4*)(z_rpo+bb+4);
    *(f4*)(out+bb)=a0v; *(f4*)(out+bb+4)=a1v;
  }
  __syncthreads();                                   // (1) x staged
  v8s xf[8];
#pragma unroll
  for (int et=0; et<2; ++et)
#pragma unroll
    for (int kt=0; kt<4; ++kt)
      xf[et*4+kt] = *(const v8s*)(xL + swzx(et*16+c, kt*4+q));
  __syncthreads();                                   // (2) xL dead -> a2L writable

  const f4 z4 = {0.f,0.f,0.f,0.f};
  float ldet[2], vv[2];                              // w1 outputs (live to epilogue)

  if (wv == 0){
    // ================= w0 phase A: actor + nst =================
    f4 acc[4][2];
#pragma unroll
    for (int wt=0; wt<4; ++wt) for (int et=0; et<2; ++et) acc[wt][et]=z4;
    gemmX<4>(ws16+AW1T, xf, acc, lane);
#pragma unroll
    for (int wt=0; wt<4; ++wt){
      const f4 bv = *(const f4*)(ab1 + wt*16 + q*4);
#pragma unroll
      for (int et=0; et<2; ++et){
        float s0=siluf(acc[wt][et][0]+bv[0]), s1=siluf(acc[wt][et][1]+bv[1]);
        float s2=siluf(acc[wt][et][2]+bv[2]), s3=siluf(acc[wt][et][3]+bv[3]);
        u32x2 u = {pk2(s0,s1), pk2(s2,s3)};
        *(u32x2*)(act0 + swz(et*16+c, wt*2+(q>>1)) + (q&1)*4) = u;
      }
    }
#pragma unroll
    for (int wt=0; wt<4; ++wt) for (int et=0; et<2; ++et) acc[wt][et]=z4;
    gemmH<4>(ws16+AW2T, act0, acc, lane, c, q);
#pragma unroll
    for (int wt=0; wt<4; ++wt){
      const f4 bv = *(const f4*)(ab2 + wt*16 + q*4);
#pragma unroll
      for (int et=0; et<2; ++et){
        float s0=siluf(acc[wt][et][0]+bv[0]), s1=siluf(acc[wt][et][1]+bv[1]);
        float s2=siluf(acc[wt][et][2]+bv[2]), s3=siluf(acc[wt][et][3]+bv[3]);
        u32x2 u = {pk2(s0,s1), pk2(s2,s3)};
        *(u32x2*)(act0 + swz(et*16+c, wt*2+(q>>1)) + (q&1)*4) = u;
      }
    }
    {
      f4 am1[1][2]; am1[0][0]=z4; am1[0][1]=z4;
      gemmH<1>(ws16+MWT, act0, am1, lane, c, q);
      if (q<2){
        const f4 mbv = *(const f4*)(mb + q*4);
#pragma unroll
        for (int et=0; et<2; ++et){
          u32x2 u = {pk2(am1[0][et][0]+mbv[0], am1[0][et][1]+mbv[1]),
                     pk2(am1[0][et][2]+mbv[2], am1[0][et][3]+mbv[3])};
          *(u32x2*)(amL + (et*16+c)*8 + q*4) = u;
        }
      }
    }
  } else {
    // ================= w1 phase A: flow a2 precompute (4 indep GEMMs) =========
#pragma unroll
    for (int i=0; i<4; ++i){
      f4 a2[2][2];
#pragma unroll
      for (int wt=0; wt<2; ++wt) for (int et=0; et<2; ++et) a2[wt][et]=z4;
      gemmX<2>(ws16+FW1XT+i*4096, xf, a2, lane);
#pragma unroll
      for (int wt=0; wt<2; ++wt)
#pragma unroll
        for (int r=0; r<4; ++r){
          const int n = wt*16 + q*4 + r;
#pragma unroll
          for (int et=0; et<2; ++et)
            a2L[(i*32 + n)*33 + et*16 + c] = a2[wt][et][r];
        }
    }
  }

  // w0 per-element nst (uses hoisted a0v/zr0v; needs amL, own wave)
  float nst[8], fld=0.f;
  if (wv==0 && l<32){
#pragma unroll
    for (int j=0;j<4;++j){
      nst[j]   = a0v[j]-b2f16(amL[l*8+j])  -zr0v[j];
      nst[4+j] = a1v[j]-b2f16(amL[l*8+4+j])-zr1v[j];
    }
    *(f4*)(nstL + l*8)     = (f4){nst[0],nst[1],nst[2],nst[3]};
    *(f4*)(nstL + l*8 + 4) = (f4){nst[4],nst[5],nst[6],nst[7]};
  }

  __syncthreads();                                   // (3) a2L ready; nstL seeded

  if (wv == 0){
    // ================= w0 phase B: flow (a2 from LDS) =================
#pragma unroll
    for (int ii=0; ii<4; ++ii){
      const int i = 3-ii;
      const int cb = (i&1)?4:0, yb = (i&1)?0:4;
      float nv[2][4];
#pragma unroll
      for (int et=0; et<2; ++et){
        const float* np = nstL + (et*16+c)*8 + cb;
        f2 t0=*(const f2*)np, t1=*(const f2*)(np+2);
        nv[et][0]=t0[0]; nv[et][1]=t0[1]; nv[et][2]=t1[0]; nv[et][3]=t1[1];
      }
#pragma unroll
      for (int wt=0; wt<2; ++wt){
        const f4 bv = *(const f4*)(fb1 + i*32 + wt*16 + q*4);
        float sh[2][4];
#pragma unroll
        for (int r=0; r<4; ++r){
          const int n = wt*16 + q*4 + r;
          const f4 wc = *(const f4*)(wsf + W1CTO + i*128 + n*4);
#pragma unroll
          for (int et=0; et<2; ++et){
            float hv = a2L[(i*32 + n)*33 + et*16 + c] + bv[r]
                     + wc[0]*nv[et][0] + wc[1]*nv[et][1]
                     + wc[2]*nv[et][2] + wc[3]*nv[et][3];
            sh[et][r] = siluf(hv);
          }
        }
#pragma unroll
        for (int et=0; et<2; ++et){
          u32x2 u = {pk2(sh[et][0],sh[et][1]), pk2(sh[et][2],sh[et][3])};
          *(u32x2*)(act0 + swz(et*16+c, wt*2+(q>>1)) + (q&1)*4) = u;
        }
      }
      // second flow layer: st = silu(hid) @ fW2 + fb2
      {
        const v8s wf3 = *(const v8s*)(ws16 + FW2T + i*512 + lane*8);
        f4 as[2];
#pragma unroll
        for (int et=0; et<2; ++et){
          const v8s hf = *(const v8s*)(act0 + swz(et*16+c, q));
          f4 a1s = z4;
          a1s = MFMA16(wf3, hf, a1s, 0,0,0);
          as[et]=a1s;
        }
        if (q<2){
          const f4 fbv = *(const f4*)(fb2 + i*8 + q*4);
#pragma unroll
          for (int et=0; et<2; ++et){
            u32x2 u = {pk2(as[et][0]+fbv[0], as[et][1]+fbv[1]),
                       pk2(as[et][2]+fbv[2], as[et][3]+fbv[3])};
            *(u32x2*)(amL + (et*16+c)*8 + q*4) = u;   // stL
          }
        }
      }
      // per-element update (lanes 0..31)
      if (l < 32){
        float sr0=b2f16(amL[l*8+0]), sr1=b2f16(amL[l*8+1]);
        float sr2=b2f16(amL[l*8+2]), sr3=b2f16(amL[l*8+3]);
        float th0=b2f16(amL[l*8+4]), th1=b2f16(amL[l*8+5]);
        float th2=b2f16(amL[l*8+6]), th3=b2f16(amL[l*8+7]);
        float s0=2.f-4.f*rcpf(__expf(2.f*sr0)+1.f);
        float s1=2.f-4.f*rcpf(__expf(2.f*sr1)+1.f);
        float s2=2.f-4.f*rcpf(__expf(2.f*sr2)+1.f);
        float s3=2.f-4.f*rcpf(__expf(2.f*sr3)+1.f);
        nst[yb+0]=(nst[yb+0]-th0)*__expf(-s0);
        nst[yb+1]=(nst[yb+1]-th1)*__expf(-s1);
        nst[yb+2]=(nst[yb+2]-th2)*__expf(-s2);
        nst[yb+3]=(nst[yb+3]-th3)*__expf(-s3);
        *(f4*)(nstL + l*8 + yb) = (f4){nst[yb+0],nst[yb+1],nst[yb+2],nst[yb+3]};
        fld += s0+s1+s2+s3;
      }
    }
    if (l < 32) fldL[l] = fld;
  } else {
    // ===== w1 phase B: t-branch and critic INTERLEAVED (independent chains) ===
    f4 accT[4][2], accC[4][2];
#pragma unroll
    for (int wt=0; wt<4; ++wt) for (int et=0; et<2; ++et){ accT[wt][et]=z4; accC[wt][et]=z4; }
    gemmX<4>(ws16+TW1T, xf, accT, lane);
    gemmX<4>(ws16+CW1T, xf, accC, lane);
    float r1[2], rc[2];
    {
      float ssT[2]={0.f,0.f}, ssC[2]={0.f,0.f};
#pragma unroll
      for (int wt=0; wt<4; ++wt){
        const f4 bvT = *(const f4*)(tb1 + wt*16 + q*4);
        const f4 rwT = *(const f4*)(t_rms1 + wt*16 + q*4);
        const f4 bvC = *(const f4*)(cb1 + wt*16 + q*4);
        const f4 rwC = *(const f4*)(c_rms + wt*16 + q*4);
#pragma unroll
        for (int et=0; et<2; ++et){
          float t0=siluf(accT[wt][et][0]+bvT[0]), t1=siluf(accT[wt][et][1]+bvT[1]);
          float t2=siluf(accT[wt][et][2]+bvT[2]), t3=siluf(accT[wt][et][3]+bvT[3]);
          ssT[et] += t0*t0+t1*t1+t2*t2+t3*t3;
          u32x2 uT = {pk2(t0*rwT[0],t1*rwT[1]), pk2(t2*rwT[2],t3*rwT[3])};
          *(u32x2*)(act1 + swz(et*16+c, wt*2+(q>>1)) + (q&1)*4) = uT;
          float c0=siluf(accC[wt][et][0]+bvC[0]), c1=siluf(accC[wt][et][1]+bvC[1]);
          float c2v=siluf(accC[wt][et][2]+bvC[2]), c3=siluf(accC[wt][et][3]+bvC[3]);
          ssC[et] += c0*c0+c1*c1+c2v*c2v+c3*c3;
          u32x2 uC = {pk2(c0*rwC[0],c1*rwC[1]), pk2(c2v*rwC[2],c3*rwC[3])};
          *(u32x2*)(act2 + swz(et*16+c, wt*2+(q>>1)) + (q&1)*4) = uC;
        }
      }
#pragma unroll
      for (int et=0; et<2; ++et){
        r1[et]=rsqrtf(qsum(ssT[et])*(1.f/64.f)+EPSF);
        rc[et]=rsqrtf(qsum(ssC[et])*(1.f/64.f)+EPSF);
      }
    }
#pragma unroll
    for (int wt=0; wt<4; ++wt) for (int et=0; et<2; ++et){ accT[wt][et]=z4; accC[wt][et]=z4; }
    gemmH<4>(ws16+TW2T, act1, accT, lane, c, q);
    gemmH<4>(ws16+CW2T, act2, accC, lane, c, q);
    // t2 activation -> act1, r2
    float r2[2];
    {
      float ss[2]={0.f,0.f};
#pragma unroll
      for (int wt=0; wt<4; ++wt){
        const f4 bv = *(const f4*)(tb2 + wt*16 + q*4);
        const f4 rw = *(const f4*)(t_rms2 + wt*16 + q*4);
#pragma unroll
        for (int et=0; et<2; ++et){
          float s0=siluf(r1[et]*accT[wt][et][0]+bv[0]), s1=siluf(r1[et]*accT[wt][et][1]+bv[1]);
          float s2=siluf(r1[et]*accT[wt][et][2]+bv[2]), s3=siluf(r1[et]*accT[wt][et][3]+bv[3]);
          ss[et] += s0*s0+s1*s1+s2*s2+s3*s3;
          u32x2 u = {pk2(s0*rw[0],s1*rw[1]), pk2(s2*rw[2],s3*rw[3])};
          *(u32x2*)(act1 + swz(et*16+c, wt*2+(q>>1)) + (q&1)*4) = u;
        }
      }
#pragma unroll
      for (int et=0; et<2; ++et) r2[et]=rsqrtf(qsum(ss[et])*(1.f/64.f)+EPSF);
    }
    // critic head (independent of chol; interleaves with it)
    {
      float vp[2]={0.f,0.f};
#pragma unroll
      for (int wt=0; wt<4; ++wt){
        const f4 bv = *(const f4*)(cb2 + wt*16 + q*4);
        const f4 wvv = *(const f4*)(cW3 + wt*16 + q*4);
#pragma unroll
        for (int et=0; et<2; ++et){
          vp[et] = fmaf(siluf(rc[et]*accC[wt][et][0]+bv[0]), wvv[0], vp[et]);
          vp[et] = fmaf(siluf(rc[et]*accC[wt][et][1]+bv[1]), wvv[1], vp[et]);
          vp[et] = fmaf(siluf(rc[et]*accC[wt][et][2]+bv[2]), wvv[2], vp[et]);
          vp[et] = fmaf(siluf(rc[et]*accC[wt][et][3]+bv[3]), wvv[3], vp[et]);
        }
      }
      const float cb3v = cb3[0];
#pragma unroll
      for (int et=0; et<2; ++et) vv[et]=qsum(vp[et])+cb3v;
    }
    // Cholesky head
    {
      f4 a3[3][2];
#pragma unroll
      for (int wt=0; wt<3; ++wt) for (int et=0; et<2; ++et) a3[wt][et]=z4;
      gemmH<3>(ws16+HWT, act1, a3, lane, c, q);
      float ldp[2]={0.f,0.f};
#pragma unroll
      for (int wt=0; wt<3; ++wt){
        const f4 hbv = *(const f4*)(wsf + HBPO + wt*16 + q*4);
#pragma unroll
        for (int et=0; et<2; ++et){
          float t0=r2[et]*a3[wt][et][0]+hbv[0], t1=r2[et]*a3[wt][et][1]+hbv[1];
          float t2=r2[et]*a3[wt][et][2]+hbv[2], t3=r2[et]*a3[wt][et][3]+hbv[3];
          if (wt==0 && q<2){
            t0=fmaxf(t0,0.f)+__logf(1.f+__expf(-fabsf(t0)));
            t1=fmaxf(t1,0.f)+__logf(1.f+__expf(-fabsf(t1)));
            t2=fmaxf(t2,0.f)+__logf(1.f+__expf(-fabsf(t2)));
            t3=fmaxf(t3,0.f)+__logf(1.f+__expf(-fabsf(t3)));
            ldp[et] += __logf(t0)+__logf(t1)+__logf(t2)+__logf(t3);
          }
          if (wt<2 || q==0){
            u32x2 u = {pk2(t0,t1), pk2(t2,t3)};
            *(u32x2*)(triL + (et*16+c)*36 + wt*16 + q*4) = u;
          }
        }
      }
#pragma unroll
      for (int et=0; et<2; ++et) ldet[et]=qsum(ldp[et]);
    }
  }

  __syncthreads();                                   // (4) nstL/fldL ready

  // ================= w1: triangular solve + outputs =================
  if (wv==1 && l<32){
    constexpr int INVPERM[36] = {0,8,1,9,10,2,11,12,13,3,14,15,16,17,4,18,19,20,
                                 21,22,5,23,24,25,26,27,28,6,29,30,31,32,33,34,35,7};
    float tri[36];
#pragma unroll
    for (int j=0;j<36;++j) tri[j] = b2f16(triL[l*36 + INVPERM[j]]);
    float nf[8];
#pragma unroll
    for (int j=0;j<8;++j) nf[j] = nstL[l*8+j];
    const float fldv = fldL[l];
    float zv[8], mahal=0.f;
#pragma unroll
    for (int r=0;r<8;++r){
      float s=nf[r];
      const int base=(r*(r+1))>>1;
#pragma unroll
      for (int cc=0;cc<r;++cc) s -= tri[base+cc]*zv[cc];
      const float z = s*rcpf(tri[base+r]);
      zv[r]=z; mahal+=z*z;
    }
    const float ldet_s = (l<16)?ldet[0]:ldet[1];
    const float v_s    = (l<16)?vv[0]:vv[1];
    const float lp = -0.5f*(8.f*LOG2PI+mahal) - ldet_s - fldv;
    const float en =  0.5f*(8.f*(1.f+LOG2PI)) + ldet_s + fldv;
    out[(size_t)Btot*8  + b0 + l] = lp;
    out[(size_t)Btot*9  + b0 + l] = en;
    out[(size_t)Btot*10 + b0 + l] = v_s;
  }
}

extern "C" void kernel_launch(void* const* d_in, const int* in_sizes, int n_in,
                              void* d_out, int out_size, void* d_ws, size_t ws_size,
                              hipStream_t stream) {
  const float* x      = (const float*)d_in[0];
  const float* action = (const float*)d_in[1];
  const float* z_rpo  = (const float*)d_in[2];
  const float* cW1    = (const float*)d_in[3];
  const float* cb1    = (const float*)d_in[4];
  const float* c_rms  = (const float*)d_in[5];
  const float* cW2    = (const float*)d_in[6];
  const float* cb2    = (const float*)d_in[7];
  const float* cW3    = (const float*)d_in[8];
  const float* cb3    = (const float*)d_in[9];
  const float* aW1    = (const float*)d_in[10];
  const float* ab1    = (const float*)d_in[11];
  const float* aW2    = (const float*)d_in[12];
  const float* ab2    = (const float*)d_in[13];
  const float* mW     = (const float*)d_in[14];
  const float* mb     = (const float*)d_in[15];
  const float* tW1    = (const float*)d_in[16];
  const float* tb1    = (const float*)d_in[17];
  const float* t_rms1 = (const float*)d_in[18];
  const float* tW2    = (const float*)d_in[19];
  const float* tb2    = (const float*)d_in[20];
  const float* t_rms2 = (const float*)d_in[21];
  const float* hW     = (const float*)d_in[22];
  const float* hb     = (const float*)d_in[23];
  const float* fW1    = (const float*)d_in[24];
  const float* fb1    = (const float*)d_in[25];
  const float* fW2    = (const float*)d_in[26];
  const float* fb2    = (const float*)d_in[27];
  float* out = (float*)d_out;

  unsigned short* ws16 = (unsigned short*)d_ws;
  float* wsf = (float*)((char*)d_ws + WS_BF16_TOTAL*2);

  const int Btot = in_sizes[0] / 128;   // 131072

  hipLaunchKernelGGL(prep_kernel, dim3(128), dim3(256), 0, stream,
                     aW1, aW2, mW, tW1, tW2, hW, hb, cW1, cW2, fW1, fW2, ws16, wsf);
  hipLaunchKernelGGL(policy_kernel, dim3(Btot/32), dim3(128), 0, stream,
                     x, action, z_rpo, cb1, c_rms, cb2, cW3, cb3,
                     ab1, ab2, mb, tb1, t_rms1, tb2, t_rms2, fb1, fb2,
                     ws16, wsf, out, Btot);
}

// Round 10
// 199.958 us; speedup vs baseline: 1.1740x; 1.1740x over previous
//
#include <hip/hip_runtime.h>

typedef __attribute__((ext_vector_type(8))) short    v8s;   // 8 bf16 (4 VGPR)
typedef __attribute__((ext_vector_type(4))) float    f4;
typedef __attribute__((ext_vector_type(2))) float    f2;
typedef __attribute__((ext_vector_type(2))) unsigned u32x2;

#define MFMA16 __builtin_amdgcn_mfma_f32_16x16x32_bf16

// ---- d_ws layout ----
// bf16 section (ushort units). ALL weight tiles are FRAGMENT-ORDERED:
//   ws[base + ((wt*KT + kt)*64 + lane)*8 + j]  holds W[n=wt*16+c][k=kt*32+q*8+j]
// -> every wf load is lane-consecutive 16B (coalesced).
#define AW1T 0        // KT=4: 16 frags
#define TW1T 8192
#define CW1T 16384
#define AW2T 24576    // KT=2: 8 frags
#define TW2T 28672
#define CW2T 32768
#define MWT  36864    // KT=2, NWT=1 (rows 8..15 zero)
#define HWT  37888    // KT=2, NWT=3 (diag-first-permuted, 36..47 zero)
#define FW1XT 40960   // + i*4096 : KT=4, NWT=2
#define FW2T  57344   // + i*512  : single frag [lane][8]
#define WS_BF16_TOTAL 59392
// f32 section (float units, base = d_ws + WS_BF16_TOTAL*2)
#define W1CTO 0       // + i*128 : [32][4]  (cond weights, row=neuron, k=0..3)
#define HBPO  512     // [48] hb permuted

#define LOG2PI 1.83787706640934548356f
#define EPSF   1.1920928955078125e-07f

__device__ __constant__ int PERM[36] = {0,2,5,9,14,20,27,35,
  1,3,4,6,7,8,10,11,12,13,15,16,17,18,19,21,22,23,24,25,26,28,29,30,31,32,33,34};

__device__ __forceinline__ float ubits(unsigned u){union{unsigned u;float f;}c;c.u=u;return c.f;}
__device__ __forceinline__ unsigned fbits(float f){union{float f;unsigned u;}c;c.f=f;return c.u;}
__device__ __forceinline__ float rcpf(float x){ return __builtin_amdgcn_rcpf(x); }
__device__ __forceinline__ float siluf(float v){ return v * rcpf(1.f + __expf(-v)); }
__device__ __forceinline__ unsigned pk2(float a,float b){            // 2x f32 -> packed bf16 (RTNE)
  unsigned ua=fbits(a); ua+=0x7fffu+((ua>>16)&1u);
  unsigned ub=fbits(b); ub+=0x7fffu+((ub>>16)&1u);
  return (ua>>16)|(ub&0xffff0000u);
}
__device__ __forceinline__ unsigned short f2bu(float a){
  unsigned ua=fbits(a); ua+=0x7fffu+((ua>>16)&1u);
  return (unsigned short)(ua>>16);
}
__device__ __forceinline__ float b2f16(unsigned short h){ return ubits(((unsigned)h)<<16); }
__device__ __forceinline__ float qsum(float v){                       // sum over the 4 quads
  v += __shfl_xor(v,16,64); v += __shfl_xor(v,32,64); return v;
}
// XOR-swizzled halfword offset into a [32][64]-bf16 tile
__device__ __forceinline__ int swz(int row, int blk){ return row*64 + ((blk ^ (row&7))*8); }
// same for the [32][128]-bf16 x tile
__device__ __forceinline__ int swzx(int row, int blk){ return row*128 + ((blk ^ (row&7))*8); }

// ============ prep: fragment-order/pad/permute weights into ws (bf16) =======
__global__ __launch_bounds__(256)
void prep_kernel(const float* __restrict__ aW1, const float* __restrict__ aW2,
                 const float* __restrict__ mW,  const float* __restrict__ tW1,
                 const float* __restrict__ tW2, const float* __restrict__ hW,
                 const float* __restrict__ hb,  const float* __restrict__ cW1,
                 const float* __restrict__ cW2, const float* __restrict__ fW1,
                 const float* __restrict__ fW2,
                 unsigned short* __restrict__ ws16, float* __restrict__ wsf)
{
  const int tid = blockIdx.x*256 + threadIdx.x;
  const int stride = gridDim.x*256;
  for (int idx=tid; idx<64*128; idx+=stride){
    int f=idx>>9, r=idx&511, lane=r>>3, j=idx&7;
    int wt=f>>2, kt=f&3, c=lane&15, q=lane>>4;
    int n=wt*16+c, k=kt*32+q*8+j;
    ws16[AW1T+idx]=f2bu(aW1[k*64+n]);
    ws16[TW1T+idx]=f2bu(tW1[k*64+n]);
    ws16[CW1T+idx]=f2bu(cW1[k*64+n]);
  }
  for (int idx=tid; idx<64*64; idx+=stride){
    int f=idx>>9, r=idx&511, lane=r>>3, j=idx&7;
    int wt=f>>1, kt=f&1, c=lane&15, q=lane>>4;
    int n=wt*16+c, k=kt*32+q*8+j;
    ws16[AW2T+idx]=f2bu(aW2[k*64+n]);
    ws16[TW2T+idx]=f2bu(tW2[k*64+n]);
    ws16[CW2T+idx]=f2bu(cW2[k*64+n]);
  }
  for (int idx=tid; idx<16*64; idx+=stride){
    int f=idx>>9, r=idx&511, lane=r>>3, j=idx&7;
    int kt=f, c=lane&15, q=lane>>4;
    int n=c, k=kt*32+q*8+j;
    ws16[MWT+idx]=f2bu(n<8 ? mW[k*8+n] : 0.f);
  }
  for (int idx=tid; idx<48*64; idx+=stride){
    int f=idx>>9, r=idx&511, lane=r>>3, j=idx&7;
    int wt=f>>1, kt=f&1, c=lane&15, q=lane>>4;
    int n=wt*16+c, k=kt*32+q*8+j;
    ws16[HWT+idx]=f2bu(n<36 ? hW[k*36+PERM[n]] : 0.f);
  }
  for (int idx=tid; idx<4*32*128; idx+=stride){
    int i=idx>>12, rem=idx&4095;
    int f=rem>>9, r=rem&511, lane=r>>3, j=idx&7;
    int wt=f>>2, kt=f&3, c=lane&15, q=lane>>4;
    int n=wt*16+c, k=kt*32+q*8+j;
    ws16[FW1XT+idx]=f2bu(fW1[i*4224 + (4+k)*32 + n]);
  }
  for (int idx=tid; idx<4*16*32; idx+=stride){
    int i=idx>>9, r=idx&511, lane=r>>3, j=idx&7;
    int c=lane&15, q=lane>>4;
    int k=q*8+j;
    ws16[FW2T+idx]=f2bu(c<8 ? fW2[i*256 + k*8 + c] : 0.f);
  }
  for (int idx=tid; idx<4*32*4; idx+=stride){
    int i=idx>>7, rem=idx&127, n=rem>>2, k=rem&3;
    wsf[W1CTO+idx]=fW1[i*4224 + k*32 + n];
  }
  for (int idx=tid; idx<48; idx+=stride)
    wsf[HBPO+idx] = idx<36 ? hb[PERM[idx]] : 0.f;
}

// ============ GEMM helpers (outputs transposed: rows=neurons, cols=elems) ===
template<int NWT>
__device__ __forceinline__ void gemmX(const unsigned short* __restrict__ Wt,
                                      const v8s* __restrict__ xf,
                                      f4 (*acc)[2], int lane)
{
#pragma unroll
  for (int kt=0; kt<4; ++kt){
    v8s wf[NWT];
#pragma unroll
    for (int wt=0; wt<NWT; ++wt)
      wf[wt] = *(const v8s*)(Wt + ((wt*4 + kt)*64 + lane)*8);
#pragma unroll
    for (int wt=0; wt<NWT; ++wt)
#pragma unroll
      for (int et=0; et<2; ++et)
        acc[wt][et] = MFMA16(wf[wt], xf[et*4+kt], acc[wt][et], 0,0,0);
  }
}

template<int NWT>
__device__ __forceinline__ void gemmH(const unsigned short* __restrict__ Wt,
                                      const unsigned short* __restrict__ actL,
                                      f4 (*acc)[2], int lane, int c, int q)
{
#pragma unroll
  for (int kt=0; kt<2; ++kt){
    v8s wf[NWT];
#pragma unroll
    for (int wt=0; wt<NWT; ++wt)
      wf[wt] = *(const v8s*)(Wt + ((wt*2 + kt)*64 + lane)*8);
    v8s af[2];
#pragma unroll
    for (int et=0; et<2; ++et)
      af[et] = *(const v8s*)(actL + swz(et*16+c, kt*4+q));
#pragma unroll
    for (int wt=0; wt<NWT; ++wt)
#pragma unroll
      for (int et=0; et<2; ++et)
        acc[wt][et] = MFMA16(wf[wt], af[et], acc[wt][et], 0,0,0);
  }
}

// ============ main: 32 elems/block, 2 waves: chain split =====================
// R8 (73us, VGPR 80, occ 22%) is the verified config. R9's accT/accC interleave
// cost +56 VGPR -> occupancy 10.9% -> 110us: ILP-by-extra-accumulators is the
// wrong currency here (registers buy occupancy; need >=20%). R10 = R8 structure
// + two register-cheap additions: hoisted action/z_rpo loads (latency under
// actor) and tri[36] preload before the last barrier (off the critical tail —
// triL writes are w1's own, same-wave ds ordering needs no barrier).
__global__ __launch_bounds__(128) __attribute__((amdgpu_waves_per_eu(3, 4)))
void policy_kernel(
    const float* __restrict__ x,    const float* __restrict__ action, const float* __restrict__ z_rpo,
    const float* __restrict__ cb1,  const float* __restrict__ c_rms,  const float* __restrict__ cb2,
    const float* __restrict__ cW3,  const float* __restrict__ cb3,
    const float* __restrict__ ab1,  const float* __restrict__ ab2,    const float* __restrict__ mb,
    const float* __restrict__ tb1,  const float* __restrict__ t_rms1, const float* __restrict__ tb2,
    const float* __restrict__ t_rms2,
    const float* __restrict__ fb1,  const float* __restrict__ fb2,
    const unsigned short* __restrict__ ws16, const float* __restrict__ wsf,
    float* __restrict__ out, const int Btot)
{
  const int tid  = threadIdx.x;
  const int wv   = tid >> 6;         // wave 0 / 1
  const int lane = tid & 63;
  const int q = lane >> 4, c = lane & 15;
  const int b0 = blockIdx.x << 5;

  __shared__ alignas(16) unsigned char smem[29056];
  float*          a2L  = (float*)smem;                     // [4][32][33] f32 flow pre-acts
  unsigned short* xL   = (unsigned short*)smem;            // [32][128] bf16 swizzled (prologue; aliases a2L)
  unsigned short* act0 = (unsigned short*)(smem + 16896);  // [32][64] bf16 swz (w0: actor / flow hid)
  unsigned short* act1 = (unsigned short*)(smem + 20992);  // [32][64] bf16 swz (w1: t/critic acts)
  unsigned short* triL = (unsigned short*)(smem + 25088);  // [32][36] bf16
  float*          nstL = (float*)(smem + 27392);           // [32][8] f32
  unsigned short* amL  = (unsigned short*)(smem + 28416);  // [32][8] bf16 (w0; stL aliases)
  float*          fldL = (float*)(smem + 28928);           // [32] f32

  // ---- stage x coalesced -> LDS (wave wv covers rows wv*16 .. wv*16+15) ----
  {
    const float* xb = x + (size_t)b0*128;
    const int rr = lane>>3, bb = (lane&7)*2;
#pragma unroll
    for (int rg=0; rg<2; ++rg){
      const int row = wv*16 + rg*8 + rr;
      const float* p = xb + row*128 + (lane&7)*16;
      f4 u0=*(const f4*)p, u1=*(const f4*)(p+4), u2=*(const f4*)(p+8), u3=*(const f4*)(p+12);
      union { unsigned u[4]; v8s v; } r0, r1;
      r0.u[0]=pk2(u0[0],u0[1]); r0.u[1]=pk2(u0[2],u0[3]);
      r0.u[2]=pk2(u1[0],u1[1]); r0.u[3]=pk2(u1[2],u1[3]);
      r1.u[0]=pk2(u2[0],u2[1]); r1.u[1]=pk2(u2[2],u2[3]);
      r1.u[2]=pk2(u3[0],u3[1]); r1.u[3]=pk2(u3[2],u3[3]);
      *(v8s*)(xL + swzx(row, bb  )) = r0.v;
      *(v8s*)(xL + swzx(row, bb+1)) = r1.v;
    }
  }
  // hoisted per-element loads (w0 lanes 0..31): overlap L2/HBM latency with actor
  const int l = lane;
  f4 a0v, a1v, zr0v, zr1v;
  if (wv==0 && l<32){
    const size_t bb = (size_t)(b0+l)*8;
    a0v=*(const f4*)(action+bb); a1v=*(const f4*)(action+bb+4);
    zr0v=*(const f4*)(z_rpo+bb); zr1v=*(const f4*)(z_rpo+bb+4);
    *(f4*)(out+bb)=a0v; *(f4*)(out+bb+4)=a1v;
  }
  __syncthreads();                                   // (1) x staged
  v8s xf[8];
#pragma unroll
  for (int et=0; et<2; ++et)
#pragma unroll
    for (int kt=0; kt<4; ++kt)
      xf[et*4+kt] = *(const v8s*)(xL + swzx(et*16+c, kt*4+q));
  __syncthreads();                                   // (2) xL dead -> a2L writable

  f4 acc[4][2];
  const f4 z4 = {0.f,0.f,0.f,0.f};
  float ldet[2], vv[2];                              // w1 outputs (live to epilogue)
  float tri[36];                                     // w1 epilogue preload

  if (wv == 0){
    // ================= w0 phase A: actor + nst =================
#pragma unroll
    for (int wt=0; wt<4; ++wt) for (int et=0; et<2; ++et) acc[wt][et]=z4;
    gemmX<4>(ws16+AW1T, xf, acc, lane);
#pragma unroll
    for (int wt=0; wt<4; ++wt){
      const f4 bv = *(const f4*)(ab1 + wt*16 + q*4);
#pragma unroll
      for (int et=0; et<2; ++et){
        float s0=siluf(acc[wt][et][0]+bv[0]), s1=siluf(acc[wt][et][1]+bv[1]);
        float s2=siluf(acc[wt][et][2]+bv[2]), s3=siluf(acc[wt][et][3]+bv[3]);
        u32x2 u = {pk2(s0,s1), pk2(s2,s3)};
        *(u32x2*)(act0 + swz(et*16+c, wt*2+(q>>1)) + (q&1)*4) = u;
      }
    }
#pragma unroll
    for (int wt=0; wt<4; ++wt) for (int et=0; et<2; ++et) acc[wt][et]=z4;
    gemmH<4>(ws16+AW2T, act0, acc, lane, c, q);
#pragma unroll
    for (int wt=0; wt<4; ++wt){
      const f4 bv = *(const f4*)(ab2 + wt*16 + q*4);
#pragma unroll
      for (int et=0; et<2; ++et){
        float s0=siluf(acc[wt][et][0]+bv[0]), s1=siluf(acc[wt][et][1]+bv[1]);
        float s2=siluf(acc[wt][et][2]+bv[2]), s3=siluf(acc[wt][et][3]+bv[3]);
        u32x2 u = {pk2(s0,s1), pk2(s2,s3)};
        *(u32x2*)(act0 + swz(et*16+c, wt*2+(q>>1)) + (q&1)*4) = u;
      }
    }
    {
      f4 am1[1][2]; am1[0][0]=z4; am1[0][1]=z4;
      gemmH<1>(ws16+MWT, act0, am1, lane, c, q);
      if (q<2){
        const f4 mbv = *(const f4*)(mb + q*4);
#pragma unroll
        for (int et=0; et<2; ++et){
          u32x2 u = {pk2(am1[0][et][0]+mbv[0], am1[0][et][1]+mbv[1]),
                     pk2(am1[0][et][2]+mbv[2], am1[0][et][3]+mbv[3])};
          *(u32x2*)(amL + (et*16+c)*8 + q*4) = u;
        }
      }
    }
  } else {
    // ================= w1 phase A: flow a2 precompute =================
#pragma unroll
    for (int i=0; i<4; ++i){
      f4 a2[2][2];
#pragma unroll
      for (int wt=0; wt<2; ++wt) for (int et=0; et<2; ++et) a2[wt][et]=z4;
      gemmX<2>(ws16+FW1XT+i*4096, xf, a2, lane);
#pragma unroll
      for (int wt=0; wt<2; ++wt)
#pragma unroll
        for (int r=0; r<4; ++r){
          const int n = wt*16 + q*4 + r;
#pragma unroll
          for (int et=0; et<2; ++et)
            a2L[(i*32 + n)*33 + et*16 + c] = a2[wt][et][r];
        }
    }
  }

  // w0 per-element nst (uses hoisted a0v/zr0v; needs amL, own wave)
  float nst[8], fld=0.f;
  if (wv==0 && l<32){
#pragma unroll
    for (int j=0;j<4;++j){
      nst[j]   = a0v[j]-b2f16(amL[l*8+j])  -zr0v[j];
      nst[4+j] = a1v[j]-b2f16(amL[l*8+4+j])-zr1v[j];
    }
    *(f4*)(nstL + l*8)     = (f4){nst[0],nst[1],nst[2],nst[3]};
    *(f4*)(nstL + l*8 + 4) = (f4){nst[4],nst[5],nst[6],nst[7]};
  }

  __syncthreads();                                   // (3) a2L ready; nstL seeded

  if (wv == 0){
    // ================= w0 phase B: flow (a2 from LDS) =================
#pragma unroll
    for (int ii=0; ii<4; ++ii){
      const int i = 3-ii;
      const int cb = (i&1)?4:0, yb = (i&1)?0:4;
      float nv[2][4];
#pragma unroll
      for (int et=0; et<2; ++et){
        const float* np = nstL + (et*16+c)*8 + cb;
        f2 t0=*(const f2*)np, t1=*(const f2*)(np+2);
        nv[et][0]=t0[0]; nv[et][1]=t0[1]; nv[et][2]=t1[0]; nv[et][3]=t1[1];
      }
#pragma unroll
      for (int wt=0; wt<2; ++wt){
        const f4 bv = *(const f4*)(fb1 + i*32 + wt*16 + q*4);
        float sh[2][4];
#pragma unroll
        for (int r=0; r<4; ++r){
          const int n = wt*16 + q*4 + r;
          const f4 wc = *(const f4*)(wsf + W1CTO + i*128 + n*4);
#pragma unroll
          for (int et=0; et<2; ++et){
            float hv = a2L[(i*32 + n)*33 + et*16 + c] + bv[r]
                     + wc[0]*nv[et][0] + wc[1]*nv[et][1]
                     + wc[2]*nv[et][2] + wc[3]*nv[et][3];
            sh[et][r] = siluf(hv);
          }
        }
#pragma unroll
        for (int et=0; et<2; ++et){
          u32x2 u = {pk2(sh[et][0],sh[et][1]), pk2(sh[et][2],sh[et][3])};
          *(u32x2*)(act0 + swz(et*16+c, wt*2+(q>>1)) + (q&1)*4) = u;
        }
      }
      // second flow layer: st = silu(hid) @ fW2 + fb2
      {
        const v8s wf3 = *(const v8s*)(ws16 + FW2T + i*512 + lane*8);
        f4 as[2];
#pragma unroll
        for (int et=0; et<2; ++et){
          const v8s hf = *(const v8s*)(act0 + swz(et*16+c, q));
          f4 a1s = z4;
          a1s = MFMA16(wf3, hf, a1s, 0,0,0);
          as[et]=a1s;
        }
        if (q<2){
          const f4 fbv = *(const f4*)(fb2 + i*8 + q*4);
#pragma unroll
          for (int et=0; et<2; ++et){
            u32x2 u = {pk2(as[et][0]+fbv[0], as[et][1]+fbv[1]),
                       pk2(as[et][2]+fbv[2], as[et][3]+fbv[3])};
            *(u32x2*)(amL + (et*16+c)*8 + q*4) = u;   // stL
          }
        }
      }
      // per-element update (lanes 0..31)
      if (l < 32){
        float sr0=b2f16(amL[l*8+0]), sr1=b2f16(amL[l*8+1]);
        float sr2=b2f16(amL[l*8+2]), sr3=b2f16(amL[l*8+3]);
        float th0=b2f16(amL[l*8+4]), th1=b2f16(amL[l*8+5]);
        float th2=b2f16(amL[l*8+6]), th3=b2f16(amL[l*8+7]);
        float s0=2.f-4.f*rcpf(__expf(2.f*sr0)+1.f);
        float s1=2.f-4.f*rcpf(__expf(2.f*sr1)+1.f);
        float s2=2.f-4.f*rcpf(__expf(2.f*sr2)+1.f);
        float s3=2.f-4.f*rcpf(__expf(2.f*sr3)+1.f);
        nst[yb+0]=(nst[yb+0]-th0)*__expf(-s0);
        nst[yb+1]=(nst[yb+1]-th1)*__expf(-s1);
        nst[yb+2]=(nst[yb+2]-th2)*__expf(-s2);
        nst[yb+3]=(nst[yb+3]-th3)*__expf(-s3);
        *(f4*)(nstL + l*8 + yb) = (f4){nst[yb+0],nst[yb+1],nst[yb+2],nst[yb+3]};
        fld += s0+s1+s2+s3;
      }
    }
    if (l < 32) fldL[l] = fld;
  } else {
    // ================= w1 phase B: t branch + critic (sequential, R8 form) ====
#pragma unroll
    for (int wt=0; wt<4; ++wt) for (int et=0; et<2; ++et) acc[wt][et]=z4;
    gemmX<4>(ws16+TW1T, xf, acc, lane);
    float r1[2];
    {
      float ss[2]={0.f,0.f};
#pragma unroll
      for (int wt=0; wt<4; ++wt){
        const f4 bv = *(const f4*)(tb1 + wt*16 + q*4);
        const f4 rw = *(const f4*)(t_rms1 + wt*16 + q*4);
#pragma unroll
        for (int et=0; et<2; ++et){
          float s0=siluf(acc[wt][et][0]+bv[0]), s1=siluf(acc[wt][et][1]+bv[1]);
          float s2=siluf(acc[wt][et][2]+bv[2]), s3=siluf(acc[wt][et][3]+bv[3]);
          ss[et] += s0*s0+s1*s1+s2*s2+s3*s3;
          u32x2 u = {pk2(s0*rw[0],s1*rw[1]), pk2(s2*rw[2],s3*rw[3])};
          *(u32x2*)(act1 + swz(et*16+c, wt*2+(q>>1)) + (q&1)*4) = u;
        }
      }
#pragma unroll
      for (int et=0; et<2; ++et) r1[et]=rsqrtf(qsum(ss[et])*(1.f/64.f)+EPSF);
    }
#pragma unroll
    for (int wt=0; wt<4; ++wt) for (int et=0; et<2; ++et) acc[wt][et]=z4;
    gemmH<4>(ws16+TW2T, act1, acc, lane, c, q);
    float r2[2];
    {
      float ss[2]={0.f,0.f};
#pragma unroll
      for (int wt=0; wt<4; ++wt){
        const f4 bv = *(const f4*)(tb2 + wt*16 + q*4);
        const f4 rw = *(const f4*)(t_rms2 + wt*16 + q*4);
#pragma unroll
        for (int et=0; et<2; ++et){
          float s0=siluf(r1[et]*acc[wt][et][0]+bv[0]), s1=siluf(r1[et]*acc[wt][et][1]+bv[1]);
          float s2=siluf(r1[et]*acc[wt][et][2]+bv[2]), s3=siluf(r1[et]*acc[wt][et][3]+bv[3]);
          ss[et] += s0*s0+s1*s1+s2*s2+s3*s3;
          u32x2 u = {pk2(s0*rw[0],s1*rw[1]), pk2(s2*rw[2],s3*rw[3])};
          *(u32x2*)(act1 + swz(et*16+c, wt*2+(q>>1)) + (q&1)*4) = u;
        }
      }
#pragma unroll
      for (int et=0; et<2; ++et) r2[et]=rsqrtf(qsum(ss[et])*(1.f/64.f)+EPSF);
    }
    // Cholesky head
    {
      f4 a3[3][2];
#pragma unroll
      for (int wt=0; wt<3; ++wt) for (int et=0; et<2; ++et) a3[wt][et]=z4;
      gemmH<3>(ws16+HWT, act1, a3, lane, c, q);
      float ldp[2]={0.f,0.f};
#pragma unroll
      for (int wt=0; wt<3; ++wt){
        const f4 hbv = *(const f4*)(wsf + HBPO + wt*16 + q*4);
#pragma unroll
        for (int et=0; et<2; ++et){
          float t0=r2[et]*a3[wt][et][0]+hbv[0], t1=r2[et]*a3[wt][et][1]+hbv[1];
          float t2=r2[et]*a3[wt][et][2]+hbv[2], t3=r2[et]*a3[wt][et][3]+hbv[3];
          if (wt==0 && q<2){
            t0=fmaxf(t0,0.f)+__logf(1.f+__expf(-fabsf(t0)));
            t1=fmaxf(t1,0.f)+__logf(1.f+__expf(-fabsf(t1)));
            t2=fmaxf(t2,0.f)+__logf(1.f+__expf(-fabsf(t2)));
            t3=fmaxf(t3,0.f)+__logf(1.f+__expf(-fabsf(t3)));
            ldp[et] += __logf(t0)+__logf(t1)+__logf(t2)+__logf(t3);
          }
          if (wt<2 || q==0){
            u32x2 u = {pk2(t0,t1), pk2(t2,t3)};
            *(u32x2*)(triL + (et*16+c)*36 + wt*16 + q*4) = u;
          }
        }
      }
#pragma unroll
      for (int et=0; et<2; ++et) ldet[et]=qsum(ldp[et]);
    }
    // critic
#pragma unroll
    for (int wt=0; wt<4; ++wt) for (int et=0; et<2; ++et) acc[wt][et]=z4;
    gemmX<4>(ws16+CW1T, xf, acc, lane);
    float rc[2];
    {
      float ss[2]={0.f,0.f};
#pragma unroll
      for (int wt=0; wt<4; ++wt){
        const f4 bv = *(const f4*)(cb1 + wt*16 + q*4);
        const f4 rw = *(const f4*)(c_rms + wt*16 + q*4);
#pragma unroll
        for (int et=0; et<2; ++et){
          float s0=siluf(acc[wt][et][0]+bv[0]), s1=siluf(acc[wt][et][1]+bv[1]);
          float s2=siluf(acc[wt][et][2]+bv[2]), s3=siluf(acc[wt][et][3]+bv[3]);
          ss[et] += s0*s0+s1*s1+s2*s2+s3*s3;
          u32x2 u = {pk2(s0*rw[0],s1*rw[1]), pk2(s2*rw[2],s3*rw[3])};
          *(u32x2*)(act1 + swz(et*16+c, wt*2+(q>>1)) + (q&1)*4) = u;
        }
      }
#pragma unroll
      for (int et=0; et<2; ++et) rc[et]=rsqrtf(qsum(ss[et])*(1.f/64.f)+EPSF);
    }
    {
#pragma unroll
      for (int wt=0; wt<4; ++wt) for (int et=0; et<2; ++et) acc[wt][et]=z4;
      gemmH<4>(ws16+CW2T, act1, acc, lane, c, q);
      float vp[2]={0.f,0.f};
#pragma unroll
      for (int wt=0; wt<4; ++wt){
        const f4 bv = *(const f4*)(cb2 + wt*16 + q*4);
        const f4 wvv = *(const f4*)(cW3 + wt*16 + q*4);
#pragma unroll
        for (int et=0; et<2; ++et){
          vp[et] = fmaf(siluf(rc[et]*acc[wt][et][0]+bv[0]), wvv[0], vp[et]);
          vp[et] = fmaf(siluf(rc[et]*acc[wt][et][1]+bv[1]), wvv[1], vp[et]);
          vp[et] = fmaf(siluf(rc[et]*acc[wt][et][2]+bv[2]), wvv[2], vp[et]);
          vp[et] = fmaf(siluf(rc[et]*acc[wt][et][3]+bv[3]), wvv[3], vp[et]);
        }
      }
      const float cb3v = cb3[0];
#pragma unroll
      for (int et=0; et<2; ++et) vv[et]=qsum(vp[et])+cb3v;
    }
    // epilogue preload: triL writes are this wave's own -> no barrier needed;
    // moves 36 LDS reads off the post-barrier critical tail
    if (l < 32){
      constexpr int INVPERM[36] = {0,8,1,9,10,2,11,12,13,3,14,15,16,17,4,18,19,20,
                                   21,22,5,23,24,25,26,27,28,6,29,30,31,32,33,34,35,7};
#pragma unroll
      for (int j=0;j<36;++j) tri[j] = b2f16(triL[l*36 + INVPERM[j]]);
    }
  }

  __syncthreads();                                   // (4) nstL/fldL ready

  // ================= w1: triangular solve + outputs =================
  if (wv==1 && l<32){
    float nf[8];
#pragma unroll
    for (int j=0;j<8;++j) nf[j] = nstL[l*8+j];
    const float fldv = fldL[l];
    float zv[8], mahal=0.f;
#pragma unroll
    for (int r=0;r<8;++r){
      float s=nf[r];
      const int base=(r*(r+1))>>1;
#pragma unroll
      for (int cc=0;cc<r;++cc) s -= tri[base+cc]*zv[cc];
      const float z = s*rcpf(tri[base+r]);
      zv[r]=z; mahal+=z*z;
    }
    const float ldet_s = (l<16)?ldet[0]:ldet[1];
    const float v_s    = (l<16)?vv[0]:vv[1];
    const float lp = -0.5f*(8.f*LOG2PI+mahal) - ldet_s - fldv;
    const float en =  0.5f*(8.f*(1.f+LOG2PI)) + ldet_s + fldv;
    out[(size_t)Btot*8  + b0 + l] = lp;
    out[(size_t)Btot*9  + b0 + l] = en;
    out[(size_t)Btot*10 + b0 + l] = v_s;
  }
}

extern "C" void kernel_launch(void* const* d_in, const int* in_sizes, int n_in,
                              void* d_out, int out_size, void* d_ws, size_t ws_size,
                              hipStream_t stream) {
  const float* x      = (const float*)d_in[0];
  const float* action = (const float*)d_in[1];
  const float* z_rpo  = (const float*)d_in[2];
  const float* cW1    = (const float*)d_in[3];
  const float* cb1    = (const float*)d_in[4];
  const float* c_rms  = (const float*)d_in[5];
  const float* cW2    = (const float*)d_in[6];
  const float* cb2    = (const float*)d_in[7];
  const float* cW3    = (const float*)d_in[8];
  const float* cb3    = (const float*)d_in[9];
  const float* aW1    = (const float*)d_in[10];
  const float* ab1    = (const float*)d_in[11];
  const float* aW2    = (const float*)d_in[12];
  const float* ab2    = (const float*)d_in[13];
  const float* mW     = (const float*)d_in[14];
  const float* mb     = (const float*)d_in[15];
  const float* tW1    = (const float*)d_in[16];
  const float* tb1    = (const float*)d_in[17];
  const float* t_rms1 = (const float*)d_in[18];
  const float* tW2    = (const float*)d_in[19];
  const float* tb2    = (const float*)d_in[20];
  const float* t_rms2 = (const float*)d_in[21];
  const float* hW     = (const float*)d_in[22];
  const float* hb     = (const float*)d_in[23];
  const float* fW1    = (const float*)d_in[24];
  const float* fb1    = (const float*)d_in[25];
  const float* fW2    = (const float*)d_in[26];
  const float* fb2    = (const float*)d_in[27];
  float* out = (float*)d_out;

  unsigned short* ws16 = (unsigned short*)d_ws;
  float* wsf = (float*)((char*)d_ws + WS_BF16_TOTAL*2);

  const int Btot = in_sizes[0] / 128;   // 131072

  hipLaunchKernelGGL(prep_kernel, dim3(128), dim3(256), 0, stream,
                     aW1, aW2, mW, tW1, tW2, hW, hb, cW1, cW2, fW1, fW2, ws16, wsf);
  hipLaunchKernelGGL(policy_kernel, dim3(Btot/32), dim3(128), 0, stream,
                     x, action, z_rpo, cb1, c_rms, cb2, cW3, cb3,
                     ab1, ab2, mb, tb1, t_rms1, tb2, t_rms2, fb1, fb2,
                     ws16, wsf, out, Btot);
}

// Round 11
// 198.893 us; speedup vs baseline: 1.1803x; 1.0054x over previous
//
#include <hip/hip_runtime.h>
#include <hip/hip_bf16.h>

typedef __attribute__((ext_vector_type(8))) short    v8s;   // 8 bf16 (4 VGPR)
typedef __attribute__((ext_vector_type(4))) float    f4;
typedef __attribute__((ext_vector_type(2))) float    f2;
typedef __attribute__((ext_vector_type(2))) unsigned u32x2;

#define MFMA16 __builtin_amdgcn_mfma_f32_16x16x32_bf16

// ---- d_ws layout ----
// bf16 section (ushort units). ALL weight tiles are FRAGMENT-ORDERED:
//   ws[base + ((wt*KT + kt)*64 + lane)*8 + j]  holds W[n=wt*16+c][k=kt*32+q*8+j]
// -> every wf load is lane-consecutive 16B (coalesced).
#define AW1T 0        // KT=4: 16 frags
#define TW1T 8192
#define CW1T 16384
#define AW2T 24576    // KT=2: 8 frags
#define TW2T 28672
#define CW2T 32768
#define MWT  36864    // KT=2, NWT=1 (rows 8..15 zero)
#define HWT  37888    // KT=2, NWT=3 (diag-first-permuted, 36..47 zero)
#define FW1XT 40960   // + i*4096 : KT=4, NWT=2
#define FW2T  57344   // + i*512  : single frag [lane][8]
#define WS_BF16_TOTAL 59392
// f32 section (float units, base = d_ws + WS_BF16_TOTAL*2)
#define W1CTO 0       // + i*128 : [32][4]  (cond weights, row=neuron, k=0..3)
#define HBPO  512     // [48] hb permuted

#define LOG2PI 1.83787706640934548356f
#define EPSF   1.1920928955078125e-07f

__device__ __constant__ int PERM[36] = {0,2,5,9,14,20,27,35,
  1,3,4,6,7,8,10,11,12,13,15,16,17,18,19,21,22,23,24,25,26,28,29,30,31,32,33,34};

__device__ __forceinline__ float ubits(unsigned u){union{unsigned u;float f;}c;c.u=u;return c.f;}
__device__ __forceinline__ unsigned fbits(float f){union{float f;unsigned u;}c;c.f=f;return c.u;}
__device__ __forceinline__ float rcpf(float x){ return __builtin_amdgcn_rcpf(x); }
__device__ __forceinline__ float siluf(float v){ return v * rcpf(1.f + __expf(-v)); }
// 2x f32 -> packed bf16 RTNE. Expressed via hip_bf16 cast so the compiler
// emits ONE v_cvt_pk_bf16_f32 instead of ~5 ALU ops of manual bias math
// (R10 PMC: VALUBusy 43% with ~150 pk2/thread on the inter-GEMM critical path).
__device__ __forceinline__ unsigned pk2(float a,float b){
  union{__hip_bfloat162 h; unsigned u;} cv;
  cv.h = __float22bfloat162_rn(make_float2(a,b));
  return cv.u;
}
__device__ __forceinline__ unsigned short f2bu(float a){
  unsigned ua=fbits(a); ua+=0x7fffu+((ua>>16)&1u);
  return (unsigned short)(ua>>16);
}
__device__ __forceinline__ float b2f16(unsigned short h){ return ubits(((unsigned)h)<<16); }
__device__ __forceinline__ float qsum(float v){                       // sum over the 4 quads
  v += __shfl_xor(v,16,64); v += __shfl_xor(v,32,64); return v;
}
// XOR-swizzled halfword offset into a [32][64]-bf16 tile
__device__ __forceinline__ int swz(int row, int blk){ return row*64 + ((blk ^ (row&7))*8); }
// same for the [32][128]-bf16 x tile
__device__ __forceinline__ int swzx(int row, int blk){ return row*128 + ((blk ^ (row&7))*8); }

// ============ prep: fragment-order/pad/permute weights into ws (bf16) =======
__global__ __launch_bounds__(256)
void prep_kernel(const float* __restrict__ aW1, const float* __restrict__ aW2,
                 const float* __restrict__ mW,  const float* __restrict__ tW1,
                 const float* __restrict__ tW2, const float* __restrict__ hW,
                 const float* __restrict__ hb,  const float* __restrict__ cW1,
                 const float* __restrict__ cW2, const float* __restrict__ fW1,
                 const float* __restrict__ fW2,
                 unsigned short* __restrict__ ws16, float* __restrict__ wsf)
{
  const int tid = blockIdx.x*256 + threadIdx.x;
  const int stride = gridDim.x*256;
  for (int idx=tid; idx<64*128; idx+=stride){
    int f=idx>>9, r=idx&511, lane=r>>3, j=idx&7;
    int wt=f>>2, kt=f&3, c=lane&15, q=lane>>4;
    int n=wt*16+c, k=kt*32+q*8+j;
    ws16[AW1T+idx]=f2bu(aW1[k*64+n]);
    ws16[TW1T+idx]=f2bu(tW1[k*64+n]);
    ws16[CW1T+idx]=f2bu(cW1[k*64+n]);
  }
  for (int idx=tid; idx<64*64; idx+=stride){
    int f=idx>>9, r=idx&511, lane=r>>3, j=idx&7;
    int wt=f>>1, kt=f&1, c=lane&15, q=lane>>4;
    int n=wt*16+c, k=kt*32+q*8+j;
    ws16[AW2T+idx]=f2bu(aW2[k*64+n]);
    ws16[TW2T+idx]=f2bu(tW2[k*64+n]);
    ws16[CW2T+idx]=f2bu(cW2[k*64+n]);
  }
  for (int idx=tid; idx<16*64; idx+=stride){
    int f=idx>>9, r=idx&511, lane=r>>3, j=idx&7;
    int kt=f, c=lane&15, q=lane>>4;
    int n=c, k=kt*32+q*8+j;
    ws16[MWT+idx]=f2bu(n<8 ? mW[k*8+n] : 0.f);
  }
  for (int idx=tid; idx<48*64; idx+=stride){
    int f=idx>>9, r=idx&511, lane=r>>3, j=idx&7;
    int wt=f>>1, kt=f&1, c=lane&15, q=lane>>4;
    int n=wt*16+c, k=kt*32+q*8+j;
    ws16[HWT+idx]=f2bu(n<36 ? hW[k*36+PERM[n]] : 0.f);
  }
  for (int idx=tid; idx<4*32*128; idx+=stride){
    int i=idx>>12, rem=idx&4095;
    int f=rem>>9, r=rem&511, lane=r>>3, j=idx&7;
    int wt=f>>2, kt=f&3, c=lane&15, q=lane>>4;
    int n=wt*16+c, k=kt*32+q*8+j;
    ws16[FW1XT+idx]=f2bu(fW1[i*4224 + (4+k)*32 + n]);
  }
  for (int idx=tid; idx<4*16*32; idx+=stride){
    int i=idx>>9, r=idx&511, lane=r>>3, j=idx&7;
    int c=lane&15, q=lane>>4;
    int k=q*8+j;
    ws16[FW2T+idx]=f2bu(c<8 ? fW2[i*256 + k*8 + c] : 0.f);
  }
  for (int idx=tid; idx<4*32*4; idx+=stride){
    int i=idx>>7, rem=idx&127, n=rem>>2, k=rem&3;
    wsf[W1CTO+idx]=fW1[i*4224 + k*32 + n];
  }
  for (int idx=tid; idx<48; idx+=stride)
    wsf[HBPO+idx] = idx<36 ? hb[PERM[idx]] : 0.f;
}

// ============ GEMM helpers (outputs transposed: rows=neurons, cols=elems) ===
template<int NWT>
__device__ __forceinline__ void gemmX(const unsigned short* __restrict__ Wt,
                                      const v8s* __restrict__ xf,
                                      f4 (*acc)[2], int lane)
{
#pragma unroll
  for (int kt=0; kt<4; ++kt){
    v8s wf[NWT];
#pragma unroll
    for (int wt=0; wt<NWT; ++wt)
      wf[wt] = *(const v8s*)(Wt + ((wt*4 + kt)*64 + lane)*8);
#pragma unroll
    for (int wt=0; wt<NWT; ++wt)
#pragma unroll
      for (int et=0; et<2; ++et)
        acc[wt][et] = MFMA16(wf[wt], xf[et*4+kt], acc[wt][et], 0,0,0);
  }
}

template<int NWT>
__device__ __forceinline__ void gemmH(const unsigned short* __restrict__ Wt,
                                      const unsigned short* __restrict__ actL,
                                      f4 (*acc)[2], int lane, int c, int q)
{
#pragma unroll
  for (int kt=0; kt<2; ++kt){
    v8s wf[NWT];
#pragma unroll
    for (int wt=0; wt<NWT; ++wt)
      wf[wt] = *(const v8s*)(Wt + ((wt*2 + kt)*64 + lane)*8);
    v8s af[2];
#pragma unroll
    for (int et=0; et<2; ++et)
      af[et] = *(const v8s*)(actL + swz(et*16+c, kt*4+q));
#pragma unroll
    for (int wt=0; wt<NWT; ++wt)
#pragma unroll
      for (int et=0; et<2; ++et)
        acc[wt][et] = MFMA16(wf[wt], af[et], acc[wt][et], 0,0,0);
  }
}

// ============ main: 32 elems/block, 2 waves: chain split =====================
// R8/R10 verified at 73us (VGPR 84, occ 22%). R11: two register-cheap VALU cuts
// on the critical chain: (1) pk2 via v_cvt_pk_bf16_f32 (compiler-emitted, ~5->1
// ops x ~150 sites/thread); (2) flow per-element exp chain spread over all 64
// lanes (2 of 4 values each, state in nstL) instead of lanes 0..31 doing 4.
__global__ __launch_bounds__(128) __attribute__((amdgpu_waves_per_eu(3, 4)))
void policy_kernel(
    const float* __restrict__ x,    const float* __restrict__ action, const float* __restrict__ z_rpo,
    const float* __restrict__ cb1,  const float* __restrict__ c_rms,  const float* __restrict__ cb2,
    const float* __restrict__ cW3,  const float* __restrict__ cb3,
    const float* __restrict__ ab1,  const float* __restrict__ ab2,    const float* __restrict__ mb,
    const float* __restrict__ tb1,  const float* __restrict__ t_rms1, const float* __restrict__ tb2,
    const float* __restrict__ t_rms2,
    const float* __restrict__ fb1,  const float* __restrict__ fb2,
    const unsigned short* __restrict__ ws16, const float* __restrict__ wsf,
    float* __restrict__ out, const int Btot)
{
  const int tid  = threadIdx.x;
  const int wv   = tid >> 6;         // wave 0 / 1
  const int lane = tid & 63;
  const int q = lane >> 4, c = lane & 15;
  const int b0 = blockIdx.x << 5;

  __shared__ alignas(16) unsigned char smem[29056];
  float*          a2L  = (float*)smem;                     // [4][32][33] f32 flow pre-acts
  unsigned short* xL   = (unsigned short*)smem;            // [32][128] bf16 swizzled (prologue; aliases a2L)
  unsigned short* act0 = (unsigned short*)(smem + 16896);  // [32][64] bf16 swz (w0: actor / flow hid)
  unsigned short* act1 = (unsigned short*)(smem + 20992);  // [32][64] bf16 swz (w1: t/critic acts)
  unsigned short* triL = (unsigned short*)(smem + 25088);  // [32][36] bf16
  float*          nstL = (float*)(smem + 27392);           // [32][8] f32
  unsigned short* amL  = (unsigned short*)(smem + 28416);  // [32][8] bf16 (w0; stL aliases)
  float*          fldL = (float*)(smem + 28928);           // [32] f32

  // ---- stage x coalesced -> LDS (wave wv covers rows wv*16 .. wv*16+15) ----
  {
    const float* xb = x + (size_t)b0*128;
    const int rr = lane>>3, bb = (lane&7)*2;
#pragma unroll
    for (int rg=0; rg<2; ++rg){
      const int row = wv*16 + rg*8 + rr;
      const float* p = xb + row*128 + (lane&7)*16;
      f4 u0=*(const f4*)p, u1=*(const f4*)(p+4), u2=*(const f4*)(p+8), u3=*(const f4*)(p+12);
      union { unsigned u[4]; v8s v; } r0, r1;
      r0.u[0]=pk2(u0[0],u0[1]); r0.u[1]=pk2(u0[2],u0[3]);
      r0.u[2]=pk2(u1[0],u1[1]); r0.u[3]=pk2(u1[2],u1[3]);
      r1.u[0]=pk2(u2[0],u2[1]); r1.u[1]=pk2(u2[2],u2[3]);
      r1.u[2]=pk2(u3[0],u3[1]); r1.u[3]=pk2(u3[2],u3[3]);
      *(v8s*)(xL + swzx(row, bb  )) = r0.v;
      *(v8s*)(xL + swzx(row, bb+1)) = r1.v;
    }
  }
  // hoisted per-element loads (w0 lanes 0..31): overlap L2/HBM latency with actor
  const int l = lane;
  f4 a0v, a1v, zr0v, zr1v;
  if (wv==0 && l<32){
    const size_t bb = (size_t)(b0+l)*8;
    a0v=*(const f4*)(action+bb); a1v=*(const f4*)(action+bb+4);
    zr0v=*(const f4*)(z_rpo+bb); zr1v=*(const f4*)(z_rpo+bb+4);
    *(f4*)(out+bb)=a0v; *(f4*)(out+bb+4)=a1v;
  }
  __syncthreads();                                   // (1) x staged
  v8s xf[8];
#pragma unroll
  for (int et=0; et<2; ++et)
#pragma unroll
    for (int kt=0; kt<4; ++kt)
      xf[et*4+kt] = *(const v8s*)(xL + swzx(et*16+c, kt*4+q));
  __syncthreads();                                   // (2) xL dead -> a2L writable

  f4 acc[4][2];
  const f4 z4 = {0.f,0.f,0.f,0.f};
  float ldet[2], vv[2];                              // w1 outputs (live to epilogue)
  float tri[36];                                     // w1 epilogue preload

  if (wv == 0){
    // ================= w0 phase A: actor + nst =================
#pragma unroll
    for (int wt=0; wt<4; ++wt) for (int et=0; et<2; ++et) acc[wt][et]=z4;
    gemmX<4>(ws16+AW1T, xf, acc, lane);
#pragma unroll
    for (int wt=0; wt<4; ++wt){
      const f4 bv = *(const f4*)(ab1 + wt*16 + q*4);
#pragma unroll
      for (int et=0; et<2; ++et){
        float s0=siluf(acc[wt][et][0]+bv[0]), s1=siluf(acc[wt][et][1]+bv[1]);
        float s2=siluf(acc[wt][et][2]+bv[2]), s3=siluf(acc[wt][et][3]+bv[3]);
        u32x2 u = {pk2(s0,s1), pk2(s2,s3)};
        *(u32x2*)(act0 + swz(et*16+c, wt*2+(q>>1)) + (q&1)*4) = u;
      }
    }
#pragma unroll
    for (int wt=0; wt<4; ++wt) for (int et=0; et<2; ++et) acc[wt][et]=z4;
    gemmH<4>(ws16+AW2T, act0, acc, lane, c, q);
#pragma unroll
    for (int wt=0; wt<4; ++wt){
      const f4 bv = *(const f4*)(ab2 + wt*16 + q*4);
#pragma unroll
      for (int et=0; et<2; ++et){
        float s0=siluf(acc[wt][et][0]+bv[0]), s1=siluf(acc[wt][et][1]+bv[1]);
        float s2=siluf(acc[wt][et][2]+bv[2]), s3=siluf(acc[wt][et][3]+bv[3]);
        u32x2 u = {pk2(s0,s1), pk2(s2,s3)};
        *(u32x2*)(act0 + swz(et*16+c, wt*2+(q>>1)) + (q&1)*4) = u;
      }
    }
    {
      f4 am1[1][2]; am1[0][0]=z4; am1[0][1]=z4;
      gemmH<1>(ws16+MWT, act0, am1, lane, c, q);
      if (q<2){
        const f4 mbv = *(const f4*)(mb + q*4);
#pragma unroll
        for (int et=0; et<2; ++et){
          u32x2 u = {pk2(am1[0][et][0]+mbv[0], am1[0][et][1]+mbv[1]),
                     pk2(am1[0][et][2]+mbv[2], am1[0][et][3]+mbv[3])};
          *(u32x2*)(amL + (et*16+c)*8 + q*4) = u;
        }
      }
    }
  } else {
    // ================= w1 phase A: flow a2 precompute =================
#pragma unroll
    for (int i=0; i<4; ++i){
      f4 a2[2][2];
#pragma unroll
      for (int wt=0; wt<2; ++wt) for (int et=0; et<2; ++et) a2[wt][et]=z4;
      gemmX<2>(ws16+FW1XT+i*4096, xf, a2, lane);
#pragma unroll
      for (int wt=0; wt<2; ++wt)
#pragma unroll
        for (int r=0; r<4; ++r){
          const int n = wt*16 + q*4 + r;
#pragma unroll
          for (int et=0; et<2; ++et)
            a2L[(i*32 + n)*33 + et*16 + c] = a2[wt][et][r];
        }
    }
  }

  // w0 per-element nst seed (uses hoisted a0v/zr0v; needs amL, own wave)
  if (wv==0 && l<32){
    float nst[8];
#pragma unroll
    for (int j=0;j<4;++j){
      nst[j]   = a0v[j]-b2f16(amL[l*8+j])  -zr0v[j];
      nst[4+j] = a1v[j]-b2f16(amL[l*8+4+j])-zr1v[j];
    }
    *(f4*)(nstL + l*8)     = (f4){nst[0],nst[1],nst[2],nst[3]};
    *(f4*)(nstL + l*8 + 4) = (f4){nst[4],nst[5],nst[6],nst[7]};
  }

  __syncthreads();                                   // (3) a2L ready; nstL seeded

  if (wv == 0){
    // ================= w0 phase B: flow (a2 from LDS; state in nstL) =========
    float fld = 0.f;                                 // partial: this lane's 2 of 4 values
    const int e = l & 31, h = l >> 5, j0 = h*2;
#pragma unroll
    for (int ii=0; ii<4; ++ii){
      const int i = 3-ii;
      const int cb = (i&1)?4:0, yb = (i&1)?0:4;
      float nv[2][4];
#pragma unroll
      for (int et=0; et<2; ++et){
        const float* np = nstL + (et*16+c)*8 + cb;
        f2 t0=*(const f2*)np, t1=*(const f2*)(np+2);
        nv[et][0]=t0[0]; nv[et][1]=t0[1]; nv[et][2]=t1[0]; nv[et][3]=t1[1];
      }
#pragma unroll
      for (int wt=0; wt<2; ++wt){
        const f4 bv = *(const f4*)(fb1 + i*32 + wt*16 + q*4);
        float sh[2][4];
#pragma unroll
        for (int r=0; r<4; ++r){
          const int n = wt*16 + q*4 + r;
          const f4 wc = *(const f4*)(wsf + W1CTO + i*128 + n*4);
#pragma unroll
          for (int et=0; et<2; ++et){
            float hv = a2L[(i*32 + n)*33 + et*16 + c] + bv[r]
                     + wc[0]*nv[et][0] + wc[1]*nv[et][1]
                     + wc[2]*nv[et][2] + wc[3]*nv[et][3];
            sh[et][r] = siluf(hv);
          }
        }
#pragma unroll
        for (int et=0; et<2; ++et){
          u32x2 u = {pk2(sh[et][0],sh[et][1]), pk2(sh[et][2],sh[et][3])};
          *(u32x2*)(act0 + swz(et*16+c, wt*2+(q>>1)) + (q&1)*4) = u;
        }
      }
      // second flow layer: st = silu(hid) @ fW2 + fb2
      {
        const v8s wf3 = *(const v8s*)(ws16 + FW2T + i*512 + lane*8);
        f4 as[2];
#pragma unroll
        for (int et=0; et<2; ++et){
          const v8s hf = *(const v8s*)(act0 + swz(et*16+c, q));
          f4 a1s = z4;
          a1s = MFMA16(wf3, hf, a1s, 0,0,0);
          as[et]=a1s;
        }
        if (q<2){
          const f4 fbv = *(const f4*)(fb2 + i*8 + q*4);
#pragma unroll
          for (int et=0; et<2; ++et){
            u32x2 u = {pk2(as[et][0]+fbv[0], as[et][1]+fbv[1]),
                       pk2(as[et][2]+fbv[2], as[et][3]+fbv[3])};
            *(u32x2*)(amL + (et*16+c)*8 + q*4) = u;   // stL
          }
        }
      }
      // per-element update: ALL 64 lanes, each handles 2 of the 4 y-values
      {
        float sr0=b2f16(amL[e*8+j0  ]), sr1=b2f16(amL[e*8+j0+1]);
        float th0=b2f16(amL[e*8+4+j0]), th1=b2f16(amL[e*8+5+j0]);
        float s0=2.f-4.f*rcpf(__expf(2.f*sr0)+1.f);
        float s1=2.f-4.f*rcpf(__expf(2.f*sr1)+1.f);
        float n0=(nstL[e*8+yb+j0  ]-th0)*__expf(-s0);
        float n1=(nstL[e*8+yb+j0+1]-th1)*__expf(-s1);
        *(f2*)(nstL + e*8 + yb + j0) = (f2){n0,n1};
        fld += s0+s1;
      }
    }
    fld += __shfl_xor(fld, 32, 64);                  // combine the two halves
    if (l < 32) fldL[l] = fld;
  } else {
    // ================= w1 phase B: t branch + critic (sequential, R8 form) ====
#pragma unroll
    for (int wt=0; wt<4; ++wt) for (int et=0; et<2; ++et) acc[wt][et]=z4;
    gemmX<4>(ws16+TW1T, xf, acc, lane);
    float r1[2];
    {
      float ss[2]={0.f,0.f};
#pragma unroll
      for (int wt=0; wt<4; ++wt){
        const f4 bv = *(const f4*)(tb1 + wt*16 + q*4);
        const f4 rw = *(const f4*)(t_rms1 + wt*16 + q*4);
#pragma unroll
        for (int et=0; et<2; ++et){
          float s0=siluf(acc[wt][et][0]+bv[0]), s1=siluf(acc[wt][et][1]+bv[1]);
          float s2=siluf(acc[wt][et][2]+bv[2]), s3=siluf(acc[wt][et][3]+bv[3]);
          ss[et] += s0*s0+s1*s1+s2*s2+s3*s3;
          u32x2 u = {pk2(s0*rw[0],s1*rw[1]), pk2(s2*rw[2],s3*rw[3])};
          *(u32x2*)(act1 + swz(et*16+c, wt*2+(q>>1)) + (q&1)*4) = u;
        }
      }
#pragma unroll
      for (int et=0; et<2; ++et) r1[et]=rsqrtf(qsum(ss[et])*(1.f/64.f)+EPSF);
    }
#pragma unroll
    for (int wt=0; wt<4; ++wt) for (int et=0; et<2; ++et) acc[wt][et]=z4;
    gemmH<4>(ws16+TW2T, act1, acc, lane, c, q);
    float r2[2];
    {
      float ss[2]={0.f,0.f};
#pragma unroll
      for (int wt=0; wt<4; ++wt){
        const f4 bv = *(const f4*)(tb2 + wt*16 + q*4);
        const f4 rw = *(const f4*)(t_rms2 + wt*16 + q*4);
#pragma unroll
        for (int et=0; et<2; ++et){
          float s0=siluf(r1[et]*acc[wt][et][0]+bv[0]), s1=siluf(r1[et]*acc[wt][et][1]+bv[1]);
          float s2=siluf(r1[et]*acc[wt][et][2]+bv[2]), s3=siluf(r1[et]*acc[wt][et][3]+bv[3]);
          ss[et] += s0*s0+s1*s1+s2*s2+s3*s3;
          u32x2 u = {pk2(s0*rw[0],s1*rw[1]), pk2(s2*rw[2],s3*rw[3])};
          *(u32x2*)(act1 + swz(et*16+c, wt*2+(q>>1)) + (q&1)*4) = u;
        }
      }
#pragma unroll
      for (int et=0; et<2; ++et) r2[et]=rsqrtf(qsum(ss[et])*(1.f/64.f)+EPSF);
    }
    // Cholesky head
    {
      f4 a3[3][2];
#pragma unroll
      for (int wt=0; wt<3; ++wt) for (int et=0; et<2; ++et) a3[wt][et]=z4;
      gemmH<3>(ws16+HWT, act1, a3, lane, c, q);
      float ldp[2]={0.f,0.f};
#pragma unroll
      for (int wt=0; wt<3; ++wt){
        const f4 hbv = *(const f4*)(wsf + HBPO + wt*16 + q*4);
#pragma unroll
        for (int et=0; et<2; ++et){
          float t0=r2[et]*a3[wt][et][0]+hbv[0], t1=r2[et]*a3[wt][et][1]+hbv[1];
          float t2=r2[et]*a3[wt][et][2]+hbv[2], t3=r2[et]*a3[wt][et][3]+hbv[3];
          if (wt==0 && q<2){
            t0=fmaxf(t0,0.f)+__logf(1.f+__expf(-fabsf(t0)));
            t1=fmaxf(t1,0.f)+__logf(1.f+__expf(-fabsf(t1)));
            t2=fmaxf(t2,0.f)+__logf(1.f+__expf(-fabsf(t2)));
            t3=fmaxf(t3,0.f)+__logf(1.f+__expf(-fabsf(t3)));
            ldp[et] += __logf(t0)+__logf(t1)+__logf(t2)+__logf(t3);
          }
          if (wt<2 || q==0){
            u32x2 u = {pk2(t0,t1), pk2(t2,t3)};
            *(u32x2*)(triL + (et*16+c)*36 + wt*16 + q*4) = u;
          }
        }
      }
#pragma unroll
      for (int et=0; et<2; ++et) ldet[et]=qsum(ldp[et]);
    }
    // critic
#pragma unroll
    for (int wt=0; wt<4; ++wt) for (int et=0; et<2; ++et) acc[wt][et]=z4;
    gemmX<4>(ws16+CW1T, xf, acc, lane);
    float rc[2];
    {
      float ss[2]={0.f,0.f};
#pragma unroll
      for (int wt=0; wt<4; ++wt){
        const f4 bv = *(const f4*)(cb1 + wt*16 + q*4);
        const f4 rw = *(const f4*)(c_rms + wt*16 + q*4);
#pragma unroll
        for (int et=0; et<2; ++et){
          float s0=siluf(acc[wt][et][0]+bv[0]), s1=siluf(acc[wt][et][1]+bv[1]);
          float s2=siluf(acc[wt][et][2]+bv[2]), s3=siluf(acc[wt][et][3]+bv[3]);
          ss[et] += s0*s0+s1*s1+s2*s2+s3*s3;
          u32x2 u = {pk2(s0*rw[0],s1*rw[1]), pk2(s2*rw[2],s3*rw[3])};
          *(u32x2*)(act1 + swz(et*16+c, wt*2+(q>>1)) + (q&1)*4) = u;
        }
      }
#pragma unroll
      for (int et=0; et<2; ++et) rc[et]=rsqrtf(qsum(ss[et])*(1.f/64.f)+EPSF);
    }
    {
#pragma unroll
      for (int wt=0; wt<4; ++wt) for (int et=0; et<2; ++et) acc[wt][et]=z4;
      gemmH<4>(ws16+CW2T, act1, acc, lane, c, q);
      float vp[2]={0.f,0.f};
#pragma unroll
      for (int wt=0; wt<4; ++wt){
        const f4 bv = *(const f4*)(cb2 + wt*16 + q*4);
        const f4 wvv = *(const f4*)(cW3 + wt*16 + q*4);
#pragma unroll
        for (int et=0; et<2; ++et){
          vp[et] = fmaf(siluf(rc[et]*acc[wt][et][0]+bv[0]), wvv[0], vp[et]);
          vp[et] = fmaf(siluf(rc[et]*acc[wt][et][1]+bv[1]), wvv[1], vp[et]);
          vp[et] = fmaf(siluf(rc[et]*acc[wt][et][2]+bv[2]), wvv[2], vp[et]);
          vp[et] = fmaf(siluf(rc[et]*acc[wt][et][3]+bv[3]), wvv[3], vp[et]);
        }
      }
      const float cb3v = cb3[0];
#pragma unroll
      for (int et=0; et<2; ++et) vv[et]=qsum(vp[et])+cb3v;
    }
    // epilogue preload: triL writes are this wave's own -> no barrier needed;
    // moves 36 LDS reads off the post-barrier critical tail
    if (l < 32){
      constexpr int INVPERM[36] = {0,8,1,9,10,2,11,12,13,3,14,15,16,17,4,18,19,20,
                                   21,22,5,23,24,25,26,27,28,6,29,30,31,32,33,34,35,7};
#pragma unroll
      for (int j=0;j<36;++j) tri[j] = b2f16(triL[l*36 + INVPERM[j]]);
    }
  }

  __syncthreads();                                   // (4) nstL/fldL ready

  // ================= w1: triangular solve + outputs =================
  if (wv==1 && l<32){
    float nf[8];
#pragma unroll
    for (int j=0;j<8;++j) nf[j] = nstL[l*8+j];
    const float fldv = fldL[l];
    float zv[8], mahal=0.f;
#pragma unroll
    for (int r=0;r<8;++r){
      float s=nf[r];
      const int base=(r*(r+1))>>1;
#pragma unroll
      for (int cc=0;cc<r;++cc) s -= tri[base+cc]*zv[cc];
      const float z = s*rcpf(tri[base+r]);
      zv[r]=z; mahal+=z*z;
    }
    const float ldet_s = (l<16)?ldet[0]:ldet[1];
    const float v_s    = (l<16)?vv[0]:vv[1];
    const float lp = -0.5f*(8.f*LOG2PI+mahal) - ldet_s - fldv;
    const float en =  0.5f*(8.f*(1.f+LOG2PI)) + ldet_s + fldv;
    out[(size_t)Btot*8  + b0 + l] = lp;
    out[(size_t)Btot*9  + b0 + l] = en;
    out[(size_t)Btot*10 + b0 + l] = v_s;
  }
}

extern "C" void kernel_launch(void* const* d_in, const int* in_sizes, int n_in,
                              void* d_out, int out_size, void* d_ws, size_t ws_size,
                              hipStream_t stream) {
  const float* x      = (const float*)d_in[0];
  const float* action = (const float*)d_in[1];
  const float* z_rpo  = (const float*)d_in[2];
  const float* cW1    = (const float*)d_in[3];
  const float* cb1    = (const float*)d_in[4];
  const float* c_rms  = (const float*)d_in[5];
  const float* cW2    = (const float*)d_in[6];
  const float* cb2    = (const float*)d_in[7];
  const float* cW3    = (const float*)d_in[8];
  const float* cb3    = (const float*)d_in[9];
  const float* aW1    = (const float*)d_in[10];
  const float* ab1    = (const float*)d_in[11];
  const float* aW2    = (const float*)d_in[12];
  const float* ab2    = (const float*)d_in[13];
  const float* mW     = (const float*)d_in[14];
  const float* mb     = (const float*)d_in[15];
  const float* tW1    = (const float*)d_in[16];
  const float* tb1    = (const float*)d_in[17];
  const float* t_rms1 = (const float*)d_in[18];
  const float* tW2    = (const float*)d_in[19];
  const float* tb2    = (const float*)d_in[20];
  const float* t_rms2 = (const float*)d_in[21];
  const float* hW     = (const float*)d_in[22];
  const float* hb     = (const float*)d_in[23];
  const float* fW1    = (const float*)d_in[24];
  const float* fb1    = (const float*)d_in[25];
  const float* fW2    = (const float*)d_in[26];
  const float* fb2    = (const float*)d_in[27];
  float* out = (float*)d_out;

  unsigned short* ws16 = (unsigned short*)d_ws;
  float* wsf = (float*)((char*)d_ws + WS_BF16_TOTAL*2);

  const int Btot = in_sizes[0] / 128;   // 131072

  hipLaunchKernelGGL(prep_kernel, dim3(128), dim3(256), 0, stream,
                     aW1, aW2, mW, tW1, tW2, hW, hb, cW1, cW2, fW1, fW2, ws16, wsf);
  hipLaunchKernelGGL(policy_kernel, dim3(Btot/32), dim3(128), 0, stream,
                     x, action, z_rpo, cb1, c_rms, cb2, cW3, cb3,
                     ab1, ab2, mb, tb1, t_rms1, tb2, t_rms2, fb1, fb2,
                     ws16, wsf, out, Btot);
}

// Round 12
// 192.596 us; speedup vs baseline: 1.2189x; 1.0327x over previous
//
#include <hip/hip_runtime.h>
#include <hip/hip_bf16.h>

typedef __attribute__((ext_vector_type(8))) short    v8s;   // 8 bf16 (4 VGPR)
typedef __attribute__((ext_vector_type(4))) float    f4;
typedef __attribute__((ext_vector_type(2))) float    f2;
typedef __attribute__((ext_vector_type(2))) unsigned u32x2;

#define MFMA16 __builtin_amdgcn_mfma_f32_16x16x32_bf16

// ---- d_ws layout ----
// bf16 section (ushort units). ALL weight tiles are FRAGMENT-ORDERED:
//   ws[base + ((wt*KT + kt)*64 + lane)*8 + j]  holds W[n=wt*16+c][k=kt*32+q*8+j]
// -> every wf load is lane-consecutive 16B (coalesced).
#define AW1T 0        // KT=4: 16 frags
#define TW1T 8192
#define CW1T 16384
#define AW2T 24576    // KT=2: 8 frags
#define TW2T 28672
#define CW2T 32768
#define MWT  36864    // KT=2, NWT=1 (rows 8..15 zero)
#define HWT  37888    // KT=2, NWT=3 (diag-first-permuted, 36..47 zero)
#define FW1XT 40960   // + i*4096 : KT=4, NWT=2
#define FW2T  57344   // + i*512  : single frag [lane][8]
#define WS_BF16_TOTAL 59392
// f32 section (float units, base = d_ws + WS_BF16_TOTAL*2)
#define W1CTO 0       // + i*128 : [32][4]  (cond weights, row=neuron, k=0..3)
#define HBPO  512     // [48] hb permuted

#define LOG2PI 1.83787706640934548356f
#define EPSF   1.1920928955078125e-07f

__device__ __constant__ int PERM[36] = {0,2,5,9,14,20,27,35,
  1,3,4,6,7,8,10,11,12,13,15,16,17,18,19,21,22,23,24,25,26,28,29,30,31,32,33,34};

__device__ __forceinline__ float ubits(unsigned u){union{unsigned u;float f;}c;c.u=u;return c.f;}
__device__ __forceinline__ unsigned fbits(float f){union{float f;unsigned u;}c;c.f=f;return c.u;}
__device__ __forceinline__ float rcpf(float x){ return __builtin_amdgcn_rcpf(x); }
__device__ __forceinline__ float siluf(float v){ return v * rcpf(1.f + __expf(-v)); }
// 2x f32 -> packed bf16 RTNE via v_cvt_pk_bf16_f32 (R11: confirmed VALU cut)
__device__ __forceinline__ unsigned pk2(float a,float b){
  union{__hip_bfloat162 h; unsigned u;} cv;
  cv.h = __float22bfloat162_rn(make_float2(a,b));
  return cv.u;
}
__device__ __forceinline__ unsigned short f2bu(float a){
  unsigned ua=fbits(a); ua+=0x7fffu+((ua>>16)&1u);
  return (unsigned short)(ua>>16);
}
__device__ __forceinline__ float b2f16(unsigned short h){ return ubits(((unsigned)h)<<16); }
__device__ __forceinline__ float qsum(float v){                       // sum over the 4 quads
  v += __shfl_xor(v,16,64); v += __shfl_xor(v,32,64); return v;
}
// XOR-swizzled halfword offset into a [32][64]-bf16 tile
__device__ __forceinline__ int swz(int row, int blk){ return row*64 + ((blk ^ (row&7))*8); }
// same for the [32][128]-bf16 x tile
__device__ __forceinline__ int swzx(int row, int blk){ return row*128 + ((blk ^ (row&7))*8); }

// ============ prep: fragment-order/pad/permute weights into ws (bf16) =======
__global__ __launch_bounds__(256)
void prep_kernel(const float* __restrict__ aW1, const float* __restrict__ aW2,
                 const float* __restrict__ mW,  const float* __restrict__ tW1,
                 const float* __restrict__ tW2, const float* __restrict__ hW,
                 const float* __restrict__ hb,  const float* __restrict__ cW1,
                 const float* __restrict__ cW2, const float* __restrict__ fW1,
                 const float* __restrict__ fW2,
                 unsigned short* __restrict__ ws16, float* __restrict__ wsf)
{
  const int tid = blockIdx.x*256 + threadIdx.x;
  const int stride = gridDim.x*256;
  for (int idx=tid; idx<64*128; idx+=stride){
    int f=idx>>9, r=idx&511, lane=r>>3, j=idx&7;
    int wt=f>>2, kt=f&3, c=lane&15, q=lane>>4;
    int n=wt*16+c, k=kt*32+q*8+j;
    ws16[AW1T+idx]=f2bu(aW1[k*64+n]);
    ws16[TW1T+idx]=f2bu(tW1[k*64+n]);
    ws16[CW1T+idx]=f2bu(cW1[k*64+n]);
  }
  for (int idx=tid; idx<64*64; idx+=stride){
    int f=idx>>9, r=idx&511, lane=r>>3, j=idx&7;
    int wt=f>>1, kt=f&1, c=lane&15, q=lane>>4;
    int n=wt*16+c, k=kt*32+q*8+j;
    ws16[AW2T+idx]=f2bu(aW2[k*64+n]);
    ws16[TW2T+idx]=f2bu(tW2[k*64+n]);
    ws16[CW2T+idx]=f2bu(cW2[k*64+n]);
  }
  for (int idx=tid; idx<16*64; idx+=stride){
    int f=idx>>9, r=idx&511, lane=r>>3, j=idx&7;
    int kt=f, c=lane&15, q=lane>>4;
    int n=c, k=kt*32+q*8+j;
    ws16[MWT+idx]=f2bu(n<8 ? mW[k*8+n] : 0.f);
  }
  for (int idx=tid; idx<48*64; idx+=stride){
    int f=idx>>9, r=idx&511, lane=r>>3, j=idx&7;
    int wt=f>>1, kt=f&1, c=lane&15, q=lane>>4;
    int n=wt*16+c, k=kt*32+q*8+j;
    ws16[HWT+idx]=f2bu(n<36 ? hW[k*36+PERM[n]] : 0.f);
  }
  for (int idx=tid; idx<4*32*128; idx+=stride){
    int i=idx>>12, rem=idx&4095;
    int f=rem>>9, r=rem&511, lane=r>>3, j=idx&7;
    int wt=f>>2, kt=f&3, c=lane&15, q=lane>>4;
    int n=wt*16+c, k=kt*32+q*8+j;
    ws16[FW1XT+idx]=f2bu(fW1[i*4224 + (4+k)*32 + n]);
  }
  for (int idx=tid; idx<4*16*32; idx+=stride){
    int i=idx>>9, r=idx&511, lane=r>>3, j=idx&7;
    int c=lane&15, q=lane>>4;
    int k=q*8+j;
    ws16[FW2T+idx]=f2bu(c<8 ? fW2[i*256 + k*8 + c] : 0.f);
  }
  for (int idx=tid; idx<4*32*4; idx+=stride){
    int i=idx>>7, rem=idx&127, n=rem>>2, k=rem&3;
    wsf[W1CTO+idx]=fW1[i*4224 + k*32 + n];
  }
  for (int idx=tid; idx<48; idx+=stride)
    wsf[HBPO+idx] = idx<36 ? hb[PERM[idx]] : 0.f;
}

// ============ GEMM helpers (outputs transposed: rows=neurons, cols=elems) ===
template<int NWT>
__device__ __forceinline__ void gemmX(const unsigned short* __restrict__ Wt,
                                      const v8s* __restrict__ xf,
                                      f4 (*acc)[2], int lane)
{
#pragma unroll
  for (int kt=0; kt<4; ++kt){
    v8s wf[NWT];
#pragma unroll
    for (int wt=0; wt<NWT; ++wt)
      wf[wt] = *(const v8s*)(Wt + ((wt*4 + kt)*64 + lane)*8);
#pragma unroll
    for (int wt=0; wt<NWT; ++wt)
#pragma unroll
      for (int et=0; et<2; ++et)
        acc[wt][et] = MFMA16(wf[wt], xf[et*4+kt], acc[wt][et], 0,0,0);
  }
}

template<int NWT>
__device__ __forceinline__ void gemmH(const unsigned short* __restrict__ Wt,
                                      const unsigned short* __restrict__ actL,
                                      f4 (*acc)[2], int lane, int c, int q)
{
#pragma unroll
  for (int kt=0; kt<2; ++kt){
    v8s wf[NWT];
#pragma unroll
    for (int wt=0; wt<NWT; ++wt)
      wf[wt] = *(const v8s*)(Wt + ((wt*2 + kt)*64 + lane)*8);
    v8s af[2];
#pragma unroll
    for (int et=0; et<2; ++et)
      af[et] = *(const v8s*)(actL + swz(et*16+c, kt*4+q));
#pragma unroll
    for (int wt=0; wt<NWT; ++wt)
#pragma unroll
      for (int et=0; et<2; ++et)
        acc[wt][et] = MFMA16(wf[wt], af[et], acc[wt][et], 0,0,0);
  }
}

// ============ main: 32 elems/block, 2 waves: chain split =====================
// R11 verified ~71us (VGPR 84, occ 22%, 29.2KB LDS -> 5 blocks/CU cap).
// R12: a2L f32 -> bf16 packed (et0|et1 in u32, [4][32][17] u32 = 8.5KB vs
// 16.9KB): LDS 29.2 -> 20.9KB -> 7 blocks/CU (waves_per_eu then caps at 12
// waves). R9/R10 showed this config IS occupancy-sensitive below ~22%;
// buying waves without touching registers or the chain. a2 is a pre-silu
// input of magnitude ~1 feeding a bf16 MFMA: bf16 rounding adds ~0.4% rel,
// absmax headroom is 0.46 vs 1.235.
__global__ __launch_bounds__(128) __attribute__((amdgpu_waves_per_eu(3, 4)))
void policy_kernel(
    const float* __restrict__ x,    const float* __restrict__ action, const float* __restrict__ z_rpo,
    const float* __restrict__ cb1,  const float* __restrict__ c_rms,  const float* __restrict__ cb2,
    const float* __restrict__ cW3,  const float* __restrict__ cb3,
    const float* __restrict__ ab1,  const float* __restrict__ ab2,    const float* __restrict__ mb,
    const float* __restrict__ tb1,  const float* __restrict__ t_rms1, const float* __restrict__ tb2,
    const float* __restrict__ t_rms2,
    const float* __restrict__ fb1,  const float* __restrict__ fb2,
    const unsigned short* __restrict__ ws16, const float* __restrict__ wsf,
    float* __restrict__ out, const int Btot)
{
  const int tid  = threadIdx.x;
  const int wv   = tid >> 6;         // wave 0 / 1
  const int lane = tid & 63;
  const int q = lane >> 4, c = lane & 15;
  const int b0 = blockIdx.x << 5;

  __shared__ alignas(16) unsigned char smem[20864];
  unsigned*       a2b  = (unsigned*)smem;                  // [4][32][17] u32: bf16 a2 (et0 lo | et1 hi)
  unsigned short* xL   = (unsigned short*)smem;            // [32][128] bf16 swizzled (prologue; aliases a2b)
  unsigned short* act0 = (unsigned short*)(smem + 8704);   // [32][64] bf16 swz (w0: actor / flow hid)
  unsigned short* act1 = (unsigned short*)(smem + 12800);  // [32][64] bf16 swz (w1: t/critic acts)
  unsigned short* triL = (unsigned short*)(smem + 16896);  // [32][36] bf16
  float*          nstL = (float*)(smem + 19200);           // [32][8] f32
  unsigned short* amL  = (unsigned short*)(smem + 20224);  // [32][8] bf16 (w0; stL aliases)
  float*          fldL = (float*)(smem + 20736);           // [32] f32

  // ---- stage x coalesced -> LDS (wave wv covers rows wv*16 .. wv*16+15) ----
  {
    const float* xb = x + (size_t)b0*128;
    const int rr = lane>>3, bb = (lane&7)*2;
#pragma unroll
    for (int rg=0; rg<2; ++rg){
      const int row = wv*16 + rg*8 + rr;
      const float* p = xb + row*128 + (lane&7)*16;
      f4 u0=*(const f4*)p, u1=*(const f4*)(p+4), u2=*(const f4*)(p+8), u3=*(const f4*)(p+12);
      union { unsigned u[4]; v8s v; } r0, r1;
      r0.u[0]=pk2(u0[0],u0[1]); r0.u[1]=pk2(u0[2],u0[3]);
      r0.u[2]=pk2(u1[0],u1[1]); r0.u[3]=pk2(u1[2],u1[3]);
      r1.u[0]=pk2(u2[0],u2[1]); r1.u[1]=pk2(u2[2],u2[3]);
      r1.u[2]=pk2(u3[0],u3[1]); r1.u[3]=pk2(u3[2],u3[3]);
      *(v8s*)(xL + swzx(row, bb  )) = r0.v;
      *(v8s*)(xL + swzx(row, bb+1)) = r1.v;
    }
  }
  // hoisted per-element loads (w0 lanes 0..31): overlap L2/HBM latency with actor
  const int l = lane;
  f4 a0v, a1v, zr0v, zr1v;
  if (wv==0 && l<32){
    const size_t bb = (size_t)(b0+l)*8;
    a0v=*(const f4*)(action+bb); a1v=*(const f4*)(action+bb+4);
    zr0v=*(const f4*)(z_rpo+bb); zr1v=*(const f4*)(z_rpo+bb+4);
    *(f4*)(out+bb)=a0v; *(f4*)(out+bb+4)=a1v;
  }
  __syncthreads();                                   // (1) x staged
  v8s xf[8];
#pragma unroll
  for (int et=0; et<2; ++et)
#pragma unroll
    for (int kt=0; kt<4; ++kt)
      xf[et*4+kt] = *(const v8s*)(xL + swzx(et*16+c, kt*4+q));
  __syncthreads();                                   // (2) xL dead -> a2b writable

  f4 acc[4][2];
  const f4 z4 = {0.f,0.f,0.f,0.f};
  float ldet[2], vv[2];                              // w1 outputs (live to epilogue)
  float tri[36];                                     // w1 epilogue preload

  if (wv == 0){
    // ================= w0 phase A: actor + nst =================
#pragma unroll
    for (int wt=0; wt<4; ++wt) for (int et=0; et<2; ++et) acc[wt][et]=z4;
    gemmX<4>(ws16+AW1T, xf, acc, lane);
#pragma unroll
    for (int wt=0; wt<4; ++wt){
      const f4 bv = *(const f4*)(ab1 + wt*16 + q*4);
#pragma unroll
      for (int et=0; et<2; ++et){
        float s0=siluf(acc[wt][et][0]+bv[0]), s1=siluf(acc[wt][et][1]+bv[1]);
        float s2=siluf(acc[wt][et][2]+bv[2]), s3=siluf(acc[wt][et][3]+bv[3]);
        u32x2 u = {pk2(s0,s1), pk2(s2,s3)};
        *(u32x2*)(act0 + swz(et*16+c, wt*2+(q>>1)) + (q&1)*4) = u;
      }
    }
#pragma unroll
    for (int wt=0; wt<4; ++wt) for (int et=0; et<2; ++et) acc[wt][et]=z4;
    gemmH<4>(ws16+AW2T, act0, acc, lane, c, q);
#pragma unroll
    for (int wt=0; wt<4; ++wt){
      const f4 bv = *(const f4*)(ab2 + wt*16 + q*4);
#pragma unroll
      for (int et=0; et<2; ++et){
        float s0=siluf(acc[wt][et][0]+bv[0]), s1=siluf(acc[wt][et][1]+bv[1]);
        float s2=siluf(acc[wt][et][2]+bv[2]), s3=siluf(acc[wt][et][3]+bv[3]);
        u32x2 u = {pk2(s0,s1), pk2(s2,s3)};
        *(u32x2*)(act0 + swz(et*16+c, wt*2+(q>>1)) + (q&1)*4) = u;
      }
    }
    {
      f4 am1[1][2]; am1[0][0]=z4; am1[0][1]=z4;
      gemmH<1>(ws16+MWT, act0, am1, lane, c, q);
      if (q<2){
        const f4 mbv = *(const f4*)(mb + q*4);
#pragma unroll
        for (int et=0; et<2; ++et){
          u32x2 u = {pk2(am1[0][et][0]+mbv[0], am1[0][et][1]+mbv[1]),
                     pk2(am1[0][et][2]+mbv[2], am1[0][et][3]+mbv[3])};
          *(u32x2*)(amL + (et*16+c)*8 + q*4) = u;
        }
      }
    }
  } else {
    // ================= w1 phase A: flow a2 precompute (bf16-packed) ==========
#pragma unroll
    for (int i=0; i<4; ++i){
      f4 a2[2][2];
#pragma unroll
      for (int wt=0; wt<2; ++wt) for (int et=0; et<2; ++et) a2[wt][et]=z4;
      gemmX<2>(ws16+FW1XT+i*4096, xf, a2, lane);
#pragma unroll
      for (int wt=0; wt<2; ++wt)
#pragma unroll
        for (int r=0; r<4; ++r){
          const int n = wt*16 + q*4 + r;
          a2b[(i*32 + n)*17 + c] = pk2(a2[wt][0][r], a2[wt][1][r]);
        }
    }
  }

  // w0 per-element nst seed (uses hoisted a0v/zr0v; needs amL, own wave)
  if (wv==0 && l<32){
    float nst[8];
#pragma unroll
    for (int j=0;j<4;++j){
      nst[j]   = a0v[j]-b2f16(amL[l*8+j])  -zr0v[j];
      nst[4+j] = a1v[j]-b2f16(amL[l*8+4+j])-zr1v[j];
    }
    *(f4*)(nstL + l*8)     = (f4){nst[0],nst[1],nst[2],nst[3]};
    *(f4*)(nstL + l*8 + 4) = (f4){nst[4],nst[5],nst[6],nst[7]};
  }

  __syncthreads();                                   // (3) a2b ready; nstL seeded

  if (wv == 0){
    // ================= w0 phase B: flow (a2 from LDS; state in nstL) =========
    float fld = 0.f;                                 // partial: this lane's 2 of 4 values
    const int e = l & 31, h = l >> 5, j0 = h*2;
#pragma unroll
    for (int ii=0; ii<4; ++ii){
      const int i = 3-ii;
      const int cb = (i&1)?4:0, yb = (i&1)?0:4;
      float nv[2][4];
#pragma unroll
      for (int et=0; et<2; ++et){
        const float* np = nstL + (et*16+c)*8 + cb;
        f2 t0=*(const f2*)np, t1=*(const f2*)(np+2);
        nv[et][0]=t0[0]; nv[et][1]=t0[1]; nv[et][2]=t1[0]; nv[et][3]=t1[1];
      }
#pragma unroll
      for (int wt=0; wt<2; ++wt){
        const f4 bv = *(const f4*)(fb1 + i*32 + wt*16 + q*4);
        float sh[2][4];
#pragma unroll
        for (int r=0; r<4; ++r){
          const int n = wt*16 + q*4 + r;
          const f4 wc = *(const f4*)(wsf + W1CTO + i*128 + n*4);
          const unsigned ua = a2b[(i*32 + n)*17 + c];
          const float a2e0 = b2f16((unsigned short)(ua & 0xffffu));
          const float a2e1 = b2f16((unsigned short)(ua >> 16));
          {
            float hv0 = a2e0 + bv[r]
                      + wc[0]*nv[0][0] + wc[1]*nv[0][1]
                      + wc[2]*nv[0][2] + wc[3]*nv[0][3];
            sh[0][r] = siluf(hv0);
            float hv1 = a2e1 + bv[r]
                      + wc[0]*nv[1][0] + wc[1]*nv[1][1]
                      + wc[2]*nv[1][2] + wc[3]*nv[1][3];
            sh[1][r] = siluf(hv1);
          }
        }
#pragma unroll
        for (int et=0; et<2; ++et){
          u32x2 u = {pk2(sh[et][0],sh[et][1]), pk2(sh[et][2],sh[et][3])};
          *(u32x2*)(act0 + swz(et*16+c, wt*2+(q>>1)) + (q&1)*4) = u;
        }
      }
      // second flow layer: st = silu(hid) @ fW2 + fb2
      {
        const v8s wf3 = *(const v8s*)(ws16 + FW2T + i*512 + lane*8);
        f4 as[2];
#pragma unroll
        for (int et=0; et<2; ++et){
          const v8s hf = *(const v8s*)(act0 + swz(et*16+c, q));
          f4 a1s = z4;
          a1s = MFMA16(wf3, hf, a1s, 0,0,0);
          as[et]=a1s;
        }
        if (q<2){
          const f4 fbv = *(const f4*)(fb2 + i*8 + q*4);
#pragma unroll
          for (int et=0; et<2; ++et){
            u32x2 u = {pk2(as[et][0]+fbv[0], as[et][1]+fbv[1]),
                       pk2(as[et][2]+fbv[2], as[et][3]+fbv[3])};
            *(u32x2*)(amL + (et*16+c)*8 + q*4) = u;   // stL
          }
        }
      }
      // per-element update: ALL 64 lanes, each handles 2 of the 4 y-values
      {
        float sr0=b2f16(amL[e*8+j0  ]), sr1=b2f16(amL[e*8+j0+1]);
        float th0=b2f16(amL[e*8+4+j0]), th1=b2f16(amL[e*8+5+j0]);
        float s0=2.f-4.f*rcpf(__expf(2.f*sr0)+1.f);
        float s1=2.f-4.f*rcpf(__expf(2.f*sr1)+1.f);
        float n0=(nstL[e*8+yb+j0  ]-th0)*__expf(-s0);
        float n1=(nstL[e*8+yb+j0+1]-th1)*__expf(-s1);
        *(f2*)(nstL + e*8 + yb + j0) = (f2){n0,n1};
        fld += s0+s1;
      }
    }
    fld += __shfl_xor(fld, 32, 64);                  // combine the two halves
    if (l < 32) fldL[l] = fld;
  } else {
    // ================= w1 phase B: t branch + critic (sequential, R8 form) ====
#pragma unroll
    for (int wt=0; wt<4; ++wt) for (int et=0; et<2; ++et) acc[wt][et]=z4;
    gemmX<4>(ws16+TW1T, xf, acc, lane);
    float r1[2];
    {
      float ss[2]={0.f,0.f};
#pragma unroll
      for (int wt=0; wt<4; ++wt){
        const f4 bv = *(const f4*)(tb1 + wt*16 + q*4);
        const f4 rw = *(const f4*)(t_rms1 + wt*16 + q*4);
#pragma unroll
        for (int et=0; et<2; ++et){
          float s0=siluf(acc[wt][et][0]+bv[0]), s1=siluf(acc[wt][et][1]+bv[1]);
          float s2=siluf(acc[wt][et][2]+bv[2]), s3=siluf(acc[wt][et][3]+bv[3]);
          ss[et] += s0*s0+s1*s1+s2*s2+s3*s3;
          u32x2 u = {pk2(s0*rw[0],s1*rw[1]), pk2(s2*rw[2],s3*rw[3])};
          *(u32x2*)(act1 + swz(et*16+c, wt*2+(q>>1)) + (q&1)*4) = u;
        }
      }
#pragma unroll
      for (int et=0; et<2; ++et) r1[et]=rsqrtf(qsum(ss[et])*(1.f/64.f)+EPSF);
    }
#pragma unroll
    for (int wt=0; wt<4; ++wt) for (int et=0; et<2; ++et) acc[wt][et]=z4;
    gemmH<4>(ws16+TW2T, act1, acc, lane, c, q);
    float r2[2];
    {
      float ss[2]={0.f,0.f};
#pragma unroll
      for (int wt=0; wt<4; ++wt){
        const f4 bv = *(const f4*)(tb2 + wt*16 + q*4);
        const f4 rw = *(const f4*)(t_rms2 + wt*16 + q*4);
#pragma unroll
        for (int et=0; et<2; ++et){
          float s0=siluf(r1[et]*acc[wt][et][0]+bv[0]), s1=siluf(r1[et]*acc[wt][et][1]+bv[1]);
          float s2=siluf(r1[et]*acc[wt][et][2]+bv[2]), s3=siluf(r1[et]*acc[wt][et][3]+bv[3]);
          ss[et] += s0*s0+s1*s1+s2*s2+s3*s3;
          u32x2 u = {pk2(s0*rw[0],s1*rw[1]), pk2(s2*rw[2],s3*rw[3])};
          *(u32x2*)(act1 + swz(et*16+c, wt*2+(q>>1)) + (q&1)*4) = u;
        }
      }
#pragma unroll
      for (int et=0; et<2; ++et) r2[et]=rsqrtf(qsum(ss[et])*(1.f/64.f)+EPSF);
    }
    // Cholesky head
    {
      f4 a3[3][2];
#pragma unroll
      for (int wt=0; wt<3; ++wt) for (int et=0; et<2; ++et) a3[wt][et]=z4;
      gemmH<3>(ws16+HWT, act1, a3, lane, c, q);
      float ldp[2]={0.f,0.f};
#pragma unroll
      for (int wt=0; wt<3; ++wt){
        const f4 hbv = *(const f4*)(wsf + HBPO + wt*16 + q*4);
#pragma unroll
        for (int et=0; et<2; ++et){
          float t0=r2[et]*a3[wt][et][0]+hbv[0], t1=r2[et]*a3[wt][et][1]+hbv[1];
          float t2=r2[et]*a3[wt][et][2]+hbv[2], t3=r2[et]*a3[wt][et][3]+hbv[3];
          if (wt==0 && q<2){
            t0=fmaxf(t0,0.f)+__logf(1.f+__expf(-fabsf(t0)));
            t1=fmaxf(t1,0.f)+__logf(1.f+__expf(-fabsf(t1)));
            t2=fmaxf(t2,0.f)+__logf(1.f+__expf(-fabsf(t2)));
            t3=fmaxf(t3,0.f)+__logf(1.f+__expf(-fabsf(t3)));
            ldp[et] += __logf(t0)+__logf(t1)+__logf(t2)+__logf(t3);
          }
          if (wt<2 || q==0){
            u32x2 u = {pk2(t0,t1), pk2(t2,t3)};
            *(u32x2*)(triL + (et*16+c)*36 + wt*16 + q*4) = u;
          }
        }
      }
#pragma unroll
      for (int et=0; et<2; ++et) ldet[et]=qsum(ldp[et]);
    }
    // critic
#pragma unroll
    for (int wt=0; wt<4; ++wt) for (int et=0; et<2; ++et) acc[wt][et]=z4;
    gemmX<4>(ws16+CW1T, xf, acc, lane);
    float rc[2];
    {
      float ss[2]={0.f,0.f};
#pragma unroll
      for (int wt=0; wt<4; ++wt){
        const f4 bv = *(const f4*)(cb1 + wt*16 + q*4);
        const f4 rw = *(const f4*)(c_rms + wt*16 + q*4);
#pragma unroll
        for (int et=0; et<2; ++et){
          float s0=siluf(acc[wt][et][0]+bv[0]), s1=siluf(acc[wt][et][1]+bv[1]);
          float s2=siluf(acc[wt][et][2]+bv[2]), s3=siluf(acc[wt][et][3]+bv[3]);
          ss[et] += s0*s0+s1*s1+s2*s2+s3*s3;
          u32x2 u = {pk2(s0*rw[0],s1*rw[1]), pk2(s2*rw[2],s3*rw[3])};
          *(u32x2*)(act1 + swz(et*16+c, wt*2+(q>>1)) + (q&1)*4) = u;
        }
      }
#pragma unroll
      for (int et=0; et<2; ++et) rc[et]=rsqrtf(qsum(ss[et])*(1.f/64.f)+EPSF);
    }
    {
#pragma unroll
      for (int wt=0; wt<4; ++wt) for (int et=0; et<2; ++et) acc[wt][et]=z4;
      gemmH<4>(ws16+CW2T, act1, acc, lane, c, q);
      float vp[2]={0.f,0.f};
#pragma unroll
      for (int wt=0; wt<4; ++wt){
        const f4 bv = *(const f4*)(cb2 + wt*16 + q*4);
        const f4 wvv = *(const f4*)(cW3 + wt*16 + q*4);
#pragma unroll
        for (int et=0; et<2; ++et){
          vp[et] = fmaf(siluf(rc[et]*acc[wt][et][0]+bv[0]), wvv[0], vp[et]);
          vp[et] = fmaf(siluf(rc[et]*acc[wt][et][1]+bv[1]), wvv[1], vp[et]);
          vp[et] = fmaf(siluf(rc[et]*acc[wt][et][2]+bv[2]), wvv[2], vp[et]);
          vp[et] = fmaf(siluf(rc[et]*acc[wt][et][3]+bv[3]), wvv[3], vp[et]);
        }
      }
      const float cb3v = cb3[0];
#pragma unroll
      for (int et=0; et<2; ++et) vv[et]=qsum(vp[et])+cb3v;
    }
    // epilogue preload: triL writes are this wave's own -> no barrier needed;
    // moves 36 LDS reads off the post-barrier critical tail
    if (l < 32){
      constexpr int INVPERM[36] = {0,8,1,9,10,2,11,12,13,3,14,15,16,17,4,18,19,20,
                                   21,22,5,23,24,25,26,27,28,6,29,30,31,32,33,34,35,7};
#pragma unroll
      for (int j=0;j<36;++j) tri[j] = b2f16(triL[l*36 + INVPERM[j]]);
    }
  }

  __syncthreads();                                   // (4) nstL/fldL ready

  // ================= w1: triangular solve + outputs =================
  if (wv==1 && l<32){
    float nf[8];
#pragma unroll
    for (int j=0;j<8;++j) nf[j] = nstL[l*8+j];
    const float fldv = fldL[l];
    float zv[8], mahal=0.f;
#pragma unroll
    for (int r=0;r<8;++r){
      float s=nf[r];
      const int base=(r*(r+1))>>1;
#pragma unroll
      for (int cc=0;cc<r;++cc) s -= tri[base+cc]*zv[cc];
      const float z = s*rcpf(tri[base+r]);
      zv[r]=z; mahal+=z*z;
    }
    const float ldet_s = (l<16)?ldet[0]:ldet[1];
    const float v_s    = (l<16)?vv[0]:vv[1];
    const float lp = -0.5f*(8.f*LOG2PI+mahal) - ldet_s - fldv;
    const float en =  0.5f*(8.f*(1.f+LOG2PI)) + ldet_s + fldv;
    out[(size_t)Btot*8  + b0 + l] = lp;
    out[(size_t)Btot*9  + b0 + l] = en;
    out[(size_t)Btot*10 + b0 + l] = v_s;
  }
}

extern "C" void kernel_launch(void* const* d_in, const int* in_sizes, int n_in,
                              void* d_out, int out_size, void* d_ws, size_t ws_size,
                              hipStream_t stream) {
  const float* x      = (const float*)d_in[0];
  const float* action = (const float*)d_in[1];
  const float* z_rpo  = (const float*)d_in[2];
  const float* cW1    = (const float*)d_in[3];
  const float* cb1    = (const float*)d_in[4];
  const float* c_rms  = (const float*)d_in[5];
  const float* cW2    = (const float*)d_in[6];
  const float* cb2    = (const float*)d_in[7];
  const float* cW3    = (const float*)d_in[8];
  const float* cb3    = (const float*)d_in[9];
  const float* aW1    = (const float*)d_in[10];
  const float* ab1    = (const float*)d_in[11];
  const float* aW2    = (const float*)d_in[12];
  const float* ab2    = (const float*)d_in[13];
  const float* mW     = (const float*)d_in[14];
  const float* mb     = (const float*)d_in[15];
  const float* tW1    = (const float*)d_in[16];
  const float* tb1    = (const float*)d_in[17];
  const float* t_rms1 = (const float*)d_in[18];
  const float* tW2    = (const float*)d_in[19];
  const float* tb2    = (const float*)d_in[20];
  const float* t_rms2 = (const float*)d_in[21];
  const float* hW     = (const float*)d_in[22];
  const float* hb     = (const float*)d_in[23];
  const float* fW1    = (const float*)d_in[24];
  const float* fb1    = (const float*)d_in[25];
  const float* fW2    = (const float*)d_in[26];
  const float* fb2    = (const float*)d_in[27];
  float* out = (float*)d_out;

  unsigned short* ws16 = (unsigned short*)d_ws;
  float* wsf = (float*)((char*)d_ws + WS_BF16_TOTAL*2);

  const int Btot = in_sizes[0] / 128;   // 131072

  hipLaunchKernelGGL(prep_kernel, dim3(128), dim3(256), 0, stream,
                     aW1, aW2, mW, tW1, tW2, hW, hb, cW1, cW2, fW1, fW2, ws16, wsf);
  hipLaunchKernelGGL(policy_kernel, dim3(Btot/32), dim3(128), 0, stream,
                     x, action, z_rpo, cb1, c_rms, cb2, cW3, cb3,
                     ab1, ab2, mb, tb1, t_rms1, tb2, t_rms2, fb1, fb2,
                     ws16, wsf, out, Btot);
}

// Round 13
// 190.451 us; speedup vs baseline: 1.2327x; 1.0113x over previous
//
#include <hip/hip_runtime.h>
#include <hip/hip_bf16.h>

typedef __attribute__((ext_vector_type(8))) short    v8s;   // 8 bf16 (4 VGPR)
typedef __attribute__((ext_vector_type(4))) float    f4;
typedef __attribute__((ext_vector_type(2))) float    f2;
typedef __attribute__((ext_vector_type(2))) unsigned u32x2;

#define MFMA16 __builtin_amdgcn_mfma_f32_16x16x32_bf16

// ---- d_ws layout ----
// bf16 section (ushort units). ALL weight tiles are FRAGMENT-ORDERED:
//   ws[base + ((wt*KT + kt)*64 + lane)*8 + j]  holds W[n=wt*16+c][k=kt*32+q*8+j]
// -> every wf load is lane-consecutive 16B (coalesced).
#define AW1T 0        // KT=4: 16 frags
#define TW1T 8192
#define CW1T 16384
#define AW2T 24576    // KT=2: 8 frags
#define TW2T 28672
#define CW2T 32768
#define MWT  36864    // KT=2, NWT=1 (rows 8..15 zero)
#define HWT  37888    // KT=2, NWT=3 (diag-first-permuted, 36..47 zero)
#define FW1XT 40960   // + i*4096 : KT=4, NWT=2
#define FW2T  57344   // + i*512  : single frag [lane][8]
#define WS_BF16_TOTAL 59392
// f32 section (float units, base = d_ws + WS_BF16_TOTAL*2)
#define W1CTO 0       // + i*128 : [32][4]  (cond weights, row=neuron, k=0..3)
#define HBPO  512     // [48] hb permuted

#define LOG2PI 1.83787706640934548356f
#define EPSF   1.1920928955078125e-07f

__device__ __constant__ int PERM[36] = {0,2,5,9,14,20,27,35,
  1,3,4,6,7,8,10,11,12,13,15,16,17,18,19,21,22,23,24,25,26,28,29,30,31,32,33,34};

__device__ __forceinline__ float ubits(unsigned u){union{unsigned u;float f;}c;c.u=u;return c.f;}
__device__ __forceinline__ unsigned fbits(float f){union{float f;unsigned u;}c;c.f=f;return c.u;}
__device__ __forceinline__ float rcpf(float x){ return __builtin_amdgcn_rcpf(x); }
__device__ __forceinline__ float siluf(float v){ return v * rcpf(1.f + __expf(-v)); }
// 2x f32 -> packed bf16 RTNE via v_cvt_pk_bf16_f32 (R11: confirmed VALU cut)
__device__ __forceinline__ unsigned pk2(float a,float b){
  union{__hip_bfloat162 h; unsigned u;} cv;
  cv.h = __float22bfloat162_rn(make_float2(a,b));
  return cv.u;
}
__device__ __forceinline__ unsigned short f2bu(float a){
  unsigned ua=fbits(a); ua+=0x7fffu+((ua>>16)&1u);
  return (unsigned short)(ua>>16);
}
__device__ __forceinline__ float b2f16(unsigned short h){ return ubits(((unsigned)h)<<16); }
__device__ __forceinline__ float qsum(float v){                       // sum over the 4 quads
  v += __shfl_xor(v,16,64); v += __shfl_xor(v,32,64); return v;
}
// XOR-swizzled halfword offset into a [32][64]-bf16 tile
__device__ __forceinline__ int swz(int row, int blk){ return row*64 + ((blk ^ (row&7))*8); }
// same for the [32][128]-bf16 x tile
__device__ __forceinline__ int swzx(int row, int blk){ return row*128 + ((blk ^ (row&7))*8); }
// a2b: [4][32][16] u32, XOR-swizzled instead of pad-17 (saves 512B -> 8 blk/CU).
// Row-pair XOR ((n&8)<<1 flips addr bit4, bijective n<->n^1) + col XOR spreads
// each 64-lane access to worst-case 2-way bank aliasing (free, m136).
__device__ __forceinline__ int a2idx(int i, int n, int c){
  return ((((i<<5)+n)<<4) ^ ((n&8)<<1)) + (c ^ ((n&7)<<1));
}

// ============ prep: fragment-order/pad/permute weights into ws (bf16) =======
__global__ __launch_bounds__(256)
void prep_kernel(const float* __restrict__ aW1, const float* __restrict__ aW2,
                 const float* __restrict__ mW,  const float* __restrict__ tW1,
                 const float* __restrict__ tW2, const float* __restrict__ hW,
                 const float* __restrict__ hb,  const float* __restrict__ cW1,
                 const float* __restrict__ cW2, const float* __restrict__ fW1,
                 const float* __restrict__ fW2,
                 unsigned short* __restrict__ ws16, float* __restrict__ wsf)
{
  const int tid = blockIdx.x*256 + threadIdx.x;
  const int stride = gridDim.x*256;
  for (int idx=tid; idx<64*128; idx+=stride){
    int f=idx>>9, r=idx&511, lane=r>>3, j=idx&7;
    int wt=f>>2, kt=f&3, c=lane&15, q=lane>>4;
    int n=wt*16+c, k=kt*32+q*8+j;
    ws16[AW1T+idx]=f2bu(aW1[k*64+n]);
    ws16[TW1T+idx]=f2bu(tW1[k*64+n]);
    ws16[CW1T+idx]=f2bu(cW1[k*64+n]);
  }
  for (int idx=tid; idx<64*64; idx+=stride){
    int f=idx>>9, r=idx&511, lane=r>>3, j=idx&7;
    int wt=f>>1, kt=f&1, c=lane&15, q=lane>>4;
    int n=wt*16+c, k=kt*32+q*8+j;
    ws16[AW2T+idx]=f2bu(aW2[k*64+n]);
    ws16[TW2T+idx]=f2bu(tW2[k*64+n]);
    ws16[CW2T+idx]=f2bu(cW2[k*64+n]);
  }
  for (int idx=tid; idx<16*64; idx+=stride){
    int f=idx>>9, r=idx&511, lane=r>>3, j=idx&7;
    int kt=f, c=lane&15, q=lane>>4;
    int n=c, k=kt*32+q*8+j;
    ws16[MWT+idx]=f2bu(n<8 ? mW[k*8+n] : 0.f);
  }
  for (int idx=tid; idx<48*64; idx+=stride){
    int f=idx>>9, r=idx&511, lane=r>>3, j=idx&7;
    int wt=f>>1, kt=f&1, c=lane&15, q=lane>>4;
    int n=wt*16+c, k=kt*32+q*8+j;
    ws16[HWT+idx]=f2bu(n<36 ? hW[k*36+PERM[n]] : 0.f);
  }
  for (int idx=tid; idx<4*32*128; idx+=stride){
    int i=idx>>12, rem=idx&4095;
    int f=rem>>9, r=rem&511, lane=r>>3, j=idx&7;
    int wt=f>>2, kt=f&3, c=lane&15, q=lane>>4;
    int n=wt*16+c, k=kt*32+q*8+j;
    ws16[FW1XT+idx]=f2bu(fW1[i*4224 + (4+k)*32 + n]);
  }
  for (int idx=tid; idx<4*16*32; idx+=stride){
    int i=idx>>9, r=idx&511, lane=r>>3, j=idx&7;
    int c=lane&15, q=lane>>4;
    int k=q*8+j;
    ws16[FW2T+idx]=f2bu(c<8 ? fW2[i*256 + k*8 + c] : 0.f);
  }
  for (int idx=tid; idx<4*32*4; idx+=stride){
    int i=idx>>7, rem=idx&127, n=rem>>2, k=rem&3;
    wsf[W1CTO+idx]=fW1[i*4224 + k*32 + n];
  }
  for (int idx=tid; idx<48; idx+=stride)
    wsf[HBPO+idx] = idx<36 ? hb[PERM[idx]] : 0.f;
}

// ============ GEMM helpers (outputs transposed: rows=neurons, cols=elems) ===
template<int NWT>
__device__ __forceinline__ void gemmX(const unsigned short* __restrict__ Wt,
                                      const v8s* __restrict__ xf,
                                      f4 (*acc)[2], int lane)
{
#pragma unroll
  for (int kt=0; kt<4; ++kt){
    v8s wf[NWT];
#pragma unroll
    for (int wt=0; wt<NWT; ++wt)
      wf[wt] = *(const v8s*)(Wt + ((wt*4 + kt)*64 + lane)*8);
#pragma unroll
    for (int wt=0; wt<NWT; ++wt)
#pragma unroll
      for (int et=0; et<2; ++et)
        acc[wt][et] = MFMA16(wf[wt], xf[et*4+kt], acc[wt][et], 0,0,0);
  }
}

template<int NWT>
__device__ __forceinline__ void gemmH(const unsigned short* __restrict__ Wt,
                                      const unsigned short* __restrict__ actL,
                                      f4 (*acc)[2], int lane, int c, int q)
{
#pragma unroll
  for (int kt=0; kt<2; ++kt){
    v8s wf[NWT];
#pragma unroll
    for (int wt=0; wt<NWT; ++wt)
      wf[wt] = *(const v8s*)(Wt + ((wt*2 + kt)*64 + lane)*8);
    v8s af[2];
#pragma unroll
    for (int et=0; et<2; ++et)
      af[et] = *(const v8s*)(actL + swz(et*16+c, kt*4+q));
#pragma unroll
    for (int wt=0; wt<NWT; ++wt)
#pragma unroll
      for (int et=0; et<2; ++et)
        acc[wt][et] = MFMA16(wf[wt], af[et], acc[wt][et], 0,0,0);
  }
}

// ============ main: 32 elems/block, 2 waves: chain split =====================
// R12 verified 65us (VGPR 84, occ 26%, LDS 20992 -> 7 blocks/CU).
// R13: a2b pad-17 -> XOR swizzle ([4][32][16] u32 = 8192B): smem 20864->20352,
// LDS block 20480 -> EXACTLY 8 blocks/CU = 16 waves = waves_per_eu(3,4) cap.
// Occupancy lever confirmed live across R9/R10/R12 (occ 10.9/21.7/26.3 ->
// dur 110/71/65); buying the last LDS-capped wave pair for free.
__global__ __launch_bounds__(128) __attribute__((amdgpu_waves_per_eu(3, 4)))
void policy_kernel(
    const float* __restrict__ x,    const float* __restrict__ action, const float* __restrict__ z_rpo,
    const float* __restrict__ cb1,  const float* __restrict__ c_rms,  const float* __restrict__ cb2,
    const float* __restrict__ cW3,  const float* __restrict__ cb3,
    const float* __restrict__ ab1,  const float* __restrict__ ab2,    const float* __restrict__ mb,
    const float* __restrict__ tb1,  const float* __restrict__ t_rms1, const float* __restrict__ tb2,
    const float* __restrict__ t_rms2,
    const float* __restrict__ fb1,  const float* __restrict__ fb2,
    const unsigned short* __restrict__ ws16, const float* __restrict__ wsf,
    float* __restrict__ out, const int Btot)
{
  const int tid  = threadIdx.x;
  const int wv   = tid >> 6;         // wave 0 / 1
  const int lane = tid & 63;
  const int q = lane >> 4, c = lane & 15;
  const int b0 = blockIdx.x << 5;

  __shared__ alignas(16) unsigned char smem[20352];
  unsigned*       a2b  = (unsigned*)smem;                  // [4][32][16] u32 XOR-swz: bf16 a2 (et0 lo | et1 hi)
  unsigned short* xL   = (unsigned short*)smem;            // [32][128] bf16 swizzled (prologue; aliases a2b)
  unsigned short* act0 = (unsigned short*)(smem + 8192);   // [32][64] bf16 swz (w0: actor / flow hid)
  unsigned short* act1 = (unsigned short*)(smem + 12288);  // [32][64] bf16 swz (w1: t/critic acts)
  unsigned short* triL = (unsigned short*)(smem + 16384);  // [32][36] bf16
  float*          nstL = (float*)(smem + 18688);           // [32][8] f32
  unsigned short* amL  = (unsigned short*)(smem + 19712);  // [32][8] bf16 (w0; stL aliases)
  float*          fldL = (float*)(smem + 20224);           // [32] f32

  // ---- stage x coalesced -> LDS (wave wv covers rows wv*16 .. wv*16+15) ----
  {
    const float* xb = x + (size_t)b0*128;
    const int rr = lane>>3, bb = (lane&7)*2;
#pragma unroll
    for (int rg=0; rg<2; ++rg){
      const int row = wv*16 + rg*8 + rr;
      const float* p = xb + row*128 + (lane&7)*16;
      f4 u0=*(const f4*)p, u1=*(const f4*)(p+4), u2=*(const f4*)(p+8), u3=*(const f4*)(p+12);
      union { unsigned u[4]; v8s v; } r0, r1;
      r0.u[0]=pk2(u0[0],u0[1]); r0.u[1]=pk2(u0[2],u0[3]);
      r0.u[2]=pk2(u1[0],u1[1]); r0.u[3]=pk2(u1[2],u1[3]);
      r1.u[0]=pk2(u2[0],u2[1]); r1.u[1]=pk2(u2[2],u2[3]);
      r1.u[2]=pk2(u3[0],u3[1]); r1.u[3]=pk2(u3[2],u3[3]);
      *(v8s*)(xL + swzx(row, bb  )) = r0.v;
      *(v8s*)(xL + swzx(row, bb+1)) = r1.v;
    }
  }
  // hoisted per-element loads (w0 lanes 0..31): overlap L2/HBM latency with actor
  const int l = lane;
  f4 a0v, a1v, zr0v, zr1v;
  if (wv==0 && l<32){
    const size_t bb = (size_t)(b0+l)*8;
    a0v=*(const f4*)(action+bb); a1v=*(const f4*)(action+bb+4);
    zr0v=*(const f4*)(z_rpo+bb); zr1v=*(const f4*)(z_rpo+bb+4);
    *(f4*)(out+bb)=a0v; *(f4*)(out+bb+4)=a1v;
  }
  __syncthreads();                                   // (1) x staged
  v8s xf[8];
#pragma unroll
  for (int et=0; et<2; ++et)
#pragma unroll
    for (int kt=0; kt<4; ++kt)
      xf[et*4+kt] = *(const v8s*)(xL + swzx(et*16+c, kt*4+q));
  __syncthreads();                                   // (2) xL dead -> a2b writable

  f4 acc[4][2];
  const f4 z4 = {0.f,0.f,0.f,0.f};
  float ldet[2], vv[2];                              // w1 outputs (live to epilogue)
  float tri[36];                                     // w1 epilogue preload

  if (wv == 0){
    // ================= w0 phase A: actor + nst =================
#pragma unroll
    for (int wt=0; wt<4; ++wt) for (int et=0; et<2; ++et) acc[wt][et]=z4;
    gemmX<4>(ws16+AW1T, xf, acc, lane);
#pragma unroll
    for (int wt=0; wt<4; ++wt){
      const f4 bv = *(const f4*)(ab1 + wt*16 + q*4);
#pragma unroll
      for (int et=0; et<2; ++et){
        float s0=siluf(acc[wt][et][0]+bv[0]), s1=siluf(acc[wt][et][1]+bv[1]);
        float s2=siluf(acc[wt][et][2]+bv[2]), s3=siluf(acc[wt][et][3]+bv[3]);
        u32x2 u = {pk2(s0,s1), pk2(s2,s3)};
        *(u32x2*)(act0 + swz(et*16+c, wt*2+(q>>1)) + (q&1)*4) = u;
      }
    }
#pragma unroll
    for (int wt=0; wt<4; ++wt) for (int et=0; et<2; ++et) acc[wt][et]=z4;
    gemmH<4>(ws16+AW2T, act0, acc, lane, c, q);
#pragma unroll
    for (int wt=0; wt<4; ++wt){
      const f4 bv = *(const f4*)(ab2 + wt*16 + q*4);
#pragma unroll
      for (int et=0; et<2; ++et){
        float s0=siluf(acc[wt][et][0]+bv[0]), s1=siluf(acc[wt][et][1]+bv[1]);
        float s2=siluf(acc[wt][et][2]+bv[2]), s3=siluf(acc[wt][et][3]+bv[3]);
        u32x2 u = {pk2(s0,s1), pk2(s2,s3)};
        *(u32x2*)(act0 + swz(et*16+c, wt*2+(q>>1)) + (q&1)*4) = u;
      }
    }
    {
      f4 am1[1][2]; am1[0][0]=z4; am1[0][1]=z4;
      gemmH<1>(ws16+MWT, act0, am1, lane, c, q);
      if (q<2){
        const f4 mbv = *(const f4*)(mb + q*4);
#pragma unroll
        for (int et=0; et<2; ++et){
          u32x2 u = {pk2(am1[0][et][0]+mbv[0], am1[0][et][1]+mbv[1]),
                     pk2(am1[0][et][2]+mbv[2], am1[0][et][3]+mbv[3])};
          *(u32x2*)(amL + (et*16+c)*8 + q*4) = u;
        }
      }
    }
  } else {
    // ================= w1 phase A: flow a2 precompute (bf16-packed, swz) =====
#pragma unroll
    for (int i=0; i<4; ++i){
      f4 a2[2][2];
#pragma unroll
      for (int wt=0; wt<2; ++wt) for (int et=0; et<2; ++et) a2[wt][et]=z4;
      gemmX<2>(ws16+FW1XT+i*4096, xf, a2, lane);
#pragma unroll
      for (int wt=0; wt<2; ++wt)
#pragma unroll
        for (int r=0; r<4; ++r){
          const int n = wt*16 + q*4 + r;
          a2b[a2idx(i, n, c)] = pk2(a2[wt][0][r], a2[wt][1][r]);
        }
    }
  }

  // w0 per-element nst seed (uses hoisted a0v/zr0v; needs amL, own wave)
  if (wv==0 && l<32){
    float nst[8];
#pragma unroll
    for (int j=0;j<4;++j){
      nst[j]   = a0v[j]-b2f16(amL[l*8+j])  -zr0v[j];
      nst[4+j] = a1v[j]-b2f16(amL[l*8+4+j])-zr1v[j];
    }
    *(f4*)(nstL + l*8)     = (f4){nst[0],nst[1],nst[2],nst[3]};
    *(f4*)(nstL + l*8 + 4) = (f4){nst[4],nst[5],nst[6],nst[7]};
  }

  __syncthreads();                                   // (3) a2b ready; nstL seeded

  if (wv == 0){
    // ================= w0 phase B: flow (a2 from LDS; state in nstL) =========
    float fld = 0.f;                                 // partial: this lane's 2 of 4 values
    const int e = l & 31, h = l >> 5, j0 = h*2;
#pragma unroll
    for (int ii=0; ii<4; ++ii){
      const int i = 3-ii;
      const int cb = (i&1)?4:0, yb = (i&1)?0:4;
      float nv[2][4];
#pragma unroll
      for (int et=0; et<2; ++et){
        const float* np = nstL + (et*16+c)*8 + cb;
        f2 t0=*(const f2*)np, t1=*(const f2*)(np+2);
        nv[et][0]=t0[0]; nv[et][1]=t0[1]; nv[et][2]=t1[0]; nv[et][3]=t1[1];
      }
#pragma unroll
      for (int wt=0; wt<2; ++wt){
        const f4 bv = *(const f4*)(fb1 + i*32 + wt*16 + q*4);
        float sh[2][4];
#pragma unroll
        for (int r=0; r<4; ++r){
          const int n = wt*16 + q*4 + r;
          const f4 wc = *(const f4*)(wsf + W1CTO + i*128 + n*4);
          const unsigned ua = a2b[a2idx(i, n, c)];
          const float a2e0 = b2f16((unsigned short)(ua & 0xffffu));
          const float a2e1 = b2f16((unsigned short)(ua >> 16));
          {
            float hv0 = a2e0 + bv[r]
                      + wc[0]*nv[0][0] + wc[1]*nv[0][1]
                      + wc[2]*nv[0][2] + wc[3]*nv[0][3];
            sh[0][r] = siluf(hv0);
            float hv1 = a2e1 + bv[r]
                      + wc[0]*nv[1][0] + wc[1]*nv[1][1]
                      + wc[2]*nv[1][2] + wc[3]*nv[1][3];
            sh[1][r] = siluf(hv1);
          }
        }
#pragma unroll
        for (int et=0; et<2; ++et){
          u32x2 u = {pk2(sh[et][0],sh[et][1]), pk2(sh[et][2],sh[et][3])};
          *(u32x2*)(act0 + swz(et*16+c, wt*2+(q>>1)) + (q&1)*4) = u;
        }
      }
      // second flow layer: st = silu(hid) @ fW2 + fb2
      {
        const v8s wf3 = *(const v8s*)(ws16 + FW2T + i*512 + lane*8);
        f4 as[2];
#pragma unroll
        for (int et=0; et<2; ++et){
          const v8s hf = *(const v8s*)(act0 + swz(et*16+c, q));
          f4 a1s = z4;
          a1s = MFMA16(wf3, hf, a1s, 0,0,0);
          as[et]=a1s;
        }
        if (q<2){
          const f4 fbv = *(const f4*)(fb2 + i*8 + q*4);
#pragma unroll
          for (int et=0; et<2; ++et){
            u32x2 u = {pk2(as[et][0]+fbv[0], as[et][1]+fbv[1]),
                       pk2(as[et][2]+fbv[2], as[et][3]+fbv[3])};
            *(u32x2*)(amL + (et*16+c)*8 + q*4) = u;   // stL
          }
        }
      }
      // per-element update: ALL 64 lanes, each handles 2 of the 4 y-values
      {
        float sr0=b2f16(amL[e*8+j0  ]), sr1=b2f16(amL[e*8+j0+1]);
        float th0=b2f16(amL[e*8+4+j0]), th1=b2f16(amL[e*8+5+j0]);
        float s0=2.f-4.f*rcpf(__expf(2.f*sr0)+1.f);
        float s1=2.f-4.f*rcpf(__expf(2.f*sr1)+1.f);
        float n0=(nstL[e*8+yb+j0  ]-th0)*__expf(-s0);
        float n1=(nstL[e*8+yb+j0+1]-th1)*__expf(-s1);
        *(f2*)(nstL + e*8 + yb + j0) = (f2){n0,n1};
        fld += s0+s1;
      }
    }
    fld += __shfl_xor(fld, 32, 64);                  // combine the two halves
    if (l < 32) fldL[l] = fld;
  } else {
    // ================= w1 phase B: t branch + critic (sequential, R8 form) ====
#pragma unroll
    for (int wt=0; wt<4; ++wt) for (int et=0; et<2; ++et) acc[wt][et]=z4;
    gemmX<4>(ws16+TW1T, xf, acc, lane);
    float r1[2];
    {
      float ss[2]={0.f,0.f};
#pragma unroll
      for (int wt=0; wt<4; ++wt){
        const f4 bv = *(const f4*)(tb1 + wt*16 + q*4);
        const f4 rw = *(const f4*)(t_rms1 + wt*16 + q*4);
#pragma unroll
        for (int et=0; et<2; ++et){
          float s0=siluf(acc[wt][et][0]+bv[0]), s1=siluf(acc[wt][et][1]+bv[1]);
          float s2=siluf(acc[wt][et][2]+bv[2]), s3=siluf(acc[wt][et][3]+bv[3]);
          ss[et] += s0*s0+s1*s1+s2*s2+s3*s3;
          u32x2 u = {pk2(s0*rw[0],s1*rw[1]), pk2(s2*rw[2],s3*rw[3])};
          *(u32x2*)(act1 + swz(et*16+c, wt*2+(q>>1)) + (q&1)*4) = u;
        }
      }
#pragma unroll
      for (int et=0; et<2; ++et) r1[et]=rsqrtf(qsum(ss[et])*(1.f/64.f)+EPSF);
    }
#pragma unroll
    for (int wt=0; wt<4; ++wt) for (int et=0; et<2; ++et) acc[wt][et]=z4;
    gemmH<4>(ws16+TW2T, act1, acc, lane, c, q);
    float r2[2];
    {
      float ss[2]={0.f,0.f};
#pragma unroll
      for (int wt=0; wt<4; ++wt){
        const f4 bv = *(const f4*)(tb2 + wt*16 + q*4);
        const f4 rw = *(const f4*)(t_rms2 + wt*16 + q*4);
#pragma unroll
        for (int et=0; et<2; ++et){
          float s0=siluf(r1[et]*acc[wt][et][0]+bv[0]), s1=siluf(r1[et]*acc[wt][et][1]+bv[1]);
          float s2=siluf(r1[et]*acc[wt][et][2]+bv[2]), s3=siluf(r1[et]*acc[wt][et][3]+bv[3]);
          ss[et] += s0*s0+s1*s1+s2*s2+s3*s3;
          u32x2 u = {pk2(s0*rw[0],s1*rw[1]), pk2(s2*rw[2],s3*rw[3])};
          *(u32x2*)(act1 + swz(et*16+c, wt*2+(q>>1)) + (q&1)*4) = u;
        }
      }
#pragma unroll
      for (int et=0; et<2; ++et) r2[et]=rsqrtf(qsum(ss[et])*(1.f/64.f)+EPSF);
    }
    // Cholesky head
    {
      f4 a3[3][2];
#pragma unroll
      for (int wt=0; wt<3; ++wt) for (int et=0; et<2; ++et) a3[wt][et]=z4;
      gemmH<3>(ws16+HWT, act1, a3, lane, c, q);
      float ldp[2]={0.f,0.f};
#pragma unroll
      for (int wt=0; wt<3; ++wt){
        const f4 hbv = *(const f4*)(wsf + HBPO + wt*16 + q*4);
#pragma unroll
        for (int et=0; et<2; ++et){
          float t0=r2[et]*a3[wt][et][0]+hbv[0], t1=r2[et]*a3[wt][et][1]+hbv[1];
          float t2=r2[et]*a3[wt][et][2]+hbv[2], t3=r2[et]*a3[wt][et][3]+hbv[3];
          if (wt==0 && q<2){
            t0=fmaxf(t0,0.f)+__logf(1.f+__expf(-fabsf(t0)));
            t1=fmaxf(t1,0.f)+__logf(1.f+__expf(-fabsf(t1)));
            t2=fmaxf(t2,0.f)+__logf(1.f+__expf(-fabsf(t2)));
            t3=fmaxf(t3,0.f)+__logf(1.f+__expf(-fabsf(t3)));
            ldp[et] += __logf(t0)+__logf(t1)+__logf(t2)+__logf(t3);
          }
          if (wt<2 || q==0){
            u32x2 u = {pk2(t0,t1), pk2(t2,t3)};
            *(u32x2*)(triL + (et*16+c)*36 + wt*16 + q*4) = u;
          }
        }
      }
#pragma unroll
      for (int et=0; et<2; ++et) ldet[et]=qsum(ldp[et]);
    }
    // critic
#pragma unroll
    for (int wt=0; wt<4; ++wt) for (int et=0; et<2; ++et) acc[wt][et]=z4;
    gemmX<4>(ws16+CW1T, xf, acc, lane);
    float rc[2];
    {
      float ss[2]={0.f,0.f};
#pragma unroll
      for (int wt=0; wt<4; ++wt){
        const f4 bv = *(const f4*)(cb1 + wt*16 + q*4);
        const f4 rw = *(const f4*)(c_rms + wt*16 + q*4);
#pragma unroll
        for (int et=0; et<2; ++et){
          float s0=siluf(acc[wt][et][0]+bv[0]), s1=siluf(acc[wt][et][1]+bv[1]);
          float s2=siluf(acc[wt][et][2]+bv[2]), s3=siluf(acc[wt][et][3]+bv[3]);
          ss[et] += s0*s0+s1*s1+s2*s2+s3*s3;
          u32x2 u = {pk2(s0*rw[0],s1*rw[1]), pk2(s2*rw[2],s3*rw[3])};
          *(u32x2*)(act1 + swz(et*16+c, wt*2+(q>>1)) + (q&1)*4) = u;
        }
      }
#pragma unroll
      for (int et=0; et<2; ++et) rc[et]=rsqrtf(qsum(ss[et])*(1.f/64.f)+EPSF);
    }
    {
#pragma unroll
      for (int wt=0; wt<4; ++wt) for (int et=0; et<2; ++et) acc[wt][et]=z4;
      gemmH<4>(ws16+CW2T, act1, acc, lane, c, q);
      float vp[2]={0.f,0.f};
#pragma unroll
      for (int wt=0; wt<4; ++wt){
        const f4 bv = *(const f4*)(cb2 + wt*16 + q*4);
        const f4 wvv = *(const f4*)(cW3 + wt*16 + q*4);
#pragma unroll
        for (int et=0; et<2; ++et){
          vp[et] = fmaf(siluf(rc[et]*acc[wt][et][0]+bv[0]), wvv[0], vp[et]);
          vp[et] = fmaf(siluf(rc[et]*acc[wt][et][1]+bv[1]), wvv[1], vp[et]);
          vp[et] = fmaf(siluf(rc[et]*acc[wt][et][2]+bv[2]), wvv[2], vp[et]);
          vp[et] = fmaf(siluf(rc[et]*acc[wt][et][3]+bv[3]), wvv[3], vp[et]);
        }
      }
      const float cb3v = cb3[0];
#pragma unroll
      for (int et=0; et<2; ++et) vv[et]=qsum(vp[et])+cb3v;
    }
    // epilogue preload: triL writes are this wave's own -> no barrier needed;
    // moves 36 LDS reads off the post-barrier critical tail
    if (l < 32){
      constexpr int INVPERM[36] = {0,8,1,9,10,2,11,12,13,3,14,15,16,17,4,18,19,20,
                                   21,22,5,23,24,25,26,27,28,6,29,30,31,32,33,34,35,7};
#pragma unroll
      for (int j=0;j<36;++j) tri[j] = b2f16(triL[l*36 + INVPERM[j]]);
    }
  }

  __syncthreads();                                   // (4) nstL/fldL ready

  // ================= w1: triangular solve + outputs =================
  if (wv==1 && l<32){
    float nf[8];
#pragma unroll
    for (int j=0;j<8;++j) nf[j] = nstL[l*8+j];
    const float fldv = fldL[l];
    float zv[8], mahal=0.f;
#pragma unroll
    for (int r=0;r<8;++r){
      float s=nf[r];
      const int base=(r*(r+1))>>1;
#pragma unroll
      for (int cc=0;cc<r;++cc) s -= tri[base+cc]*zv[cc];
      const float z = s*rcpf(tri[base+r]);
      zv[r]=z; mahal+=z*z;
    }
    const float ldet_s = (l<16)?ldet[0]:ldet[1];
    const float v_s    = (l<16)?vv[0]:vv[1];
    const float lp = -0.5f*(8.f*LOG2PI+mahal) - ldet_s - fldv;
    const float en =  0.5f*(8.f*(1.f+LOG2PI)) + ldet_s + fldv;
    out[(size_t)Btot*8  + b0 + l] = lp;
    out[(size_t)Btot*9  + b0 + l] = en;
    out[(size_t)Btot*10 + b0 + l] = v_s;
  }
}

extern "C" void kernel_launch(void* const* d_in, const int* in_sizes, int n_in,
                              void* d_out, int out_size, void* d_ws, size_t ws_size,
                              hipStream_t stream) {
  const float* x      = (const float*)d_in[0];
  const float* action = (const float*)d_in[1];
  const float* z_rpo  = (const float*)d_in[2];
  const float* cW1    = (const float*)d_in[3];
  const float* cb1    = (const float*)d_in[4];
  const float* c_rms  = (const float*)d_in[5];
  const float* cW2    = (const float*)d_in[6];
  const float* cb2    = (const float*)d_in[7];
  const float* cW3    = (const float*)d_in[8];
  const float* cb3    = (const float*)d_in[9];
  const float* aW1    = (const float*)d_in[10];
  const float* ab1    = (const float*)d_in[11];
  const float* aW2    = (const float*)d_in[12];
  const float* ab2    = (const float*)d_in[13];
  const float* mW     = (const float*)d_in[14];
  const float* mb     = (const float*)d_in[15];
  const float* tW1    = (const float*)d_in[16];
  const float* tb1    = (const float*)d_in[17];
  const float* t_rms1 = (const float*)d_in[18];
  const float* tW2    = (const float*)d_in[19];
  const float* tb2    = (const float*)d_in[20];
  const float* t_rms2 = (const float*)d_in[21];
  const float* hW     = (const float*)d_in[22];
  const float* hb     = (const float*)d_in[23];
  const float* fW1    = (const float*)d_in[24];
  const float* fb1    = (const float*)d_in[25];
  const float* fW2    = (const float*)d_in[26];
  const float* fb2    = (const float*)d_in[27];
  float* out = (float*)d_out;

  unsigned short* ws16 = (unsigned short*)d_ws;
  float* wsf = (float*)((char*)d_ws + WS_BF16_TOTAL*2);

  const int Btot = in_sizes[0] / 128;   // 131072

  hipLaunchKernelGGL(prep_kernel, dim3(128), dim3(256), 0, stream,
                     aW1, aW2, mW, tW1, tW2, hW, hb, cW1, cW2, fW1, fW2, ws16, wsf);
  hipLaunchKernelGGL(policy_kernel, dim3(Btot/32), dim3(128), 0, stream,
                     x, action, z_rpo, cb1, c_rms, cb2, cW3, cb3,
                     ab1, ab2, mb, tb1, t_rms1, tb2, t_rms2, fb1, fb2,
                     ws16, wsf, out, Btot);
}